// Round 4
// baseline (4274.594 us; speedup 1.0000x reference)
//
#include <hip/hip_runtime.h>
#include <math.h>

#define HID 64
#define BSHIFT 6
#define BNODES 64
#define SRCBITS 17
#define SRCMASK ((1 << SRCBITS) - 1)
#define MAXBUCK 2048
#define ELLW 96

// ================= small utility =================
__global__ void k_zero_int(int* __restrict__ p, int n) {
    int i = blockIdx.x * blockDim.x + threadIdx.x;
    if (i < n) p[i] = 0;
}

// ================= bucket histogram (LDS-staged) =================
__global__ void k_hist(const int* __restrict__ dst, int* __restrict__ gcnt, int E, int nb) {
    __shared__ int lh[MAXBUCK];
    for (int t = threadIdx.x; t < nb; t += 256) lh[t] = 0;
    __syncthreads();
    for (int e = blockIdx.x * 256 + threadIdx.x; e < E; e += gridDim.x * 256)
        atomicAdd(&lh[dst[e] >> BSHIFT], 1);
    __syncthreads();
    for (int t = threadIdx.x; t < nb; t += 256) {
        int v = lh[t];
        if (v) atomicAdd(&gcnt[t], v);
    }
}

// ================= exclusive scan of up to 2048 bucket counts (1 block) =================
__global__ void k_scan2(const int* __restrict__ cnt, int* __restrict__ offs, int nb) {
    __shared__ int lds[1024];
    int t = threadIdx.x;
    int a = (2 * t < nb) ? cnt[2 * t] : 0;
    int bb = (2 * t + 1 < nb) ? cnt[2 * t + 1] : 0;
    lds[t] = a + bb;
    __syncthreads();
    for (int off = 1; off < 1024; off <<= 1) {
        int v = (t >= off) ? lds[t - off] : 0;
        __syncthreads();
        lds[t] += v;
        __syncthreads();
    }
    int excl = (t == 0) ? 0 : lds[t - 1];
    if (2 * t < nb) offs[2 * t] = excl;
    if (2 * t + 1 < nb) offs[2 * t + 1] = excl + a;
    if (2 * t + 1 == nb) offs[nb] = excl + a;
    if (2 * t + 2 == nb) offs[nb] = excl + a + bb;
}

// ================= partition: pack (dstLocal, src) into bucket regions =================
__global__ void k_part_scatter(const int* __restrict__ src, const int* __restrict__ dst,
                               const int* __restrict__ offs, int* __restrict__ gcur,
                               int* __restrict__ part, int E) {
    int e = blockIdx.x * 256 + threadIdx.x;
    if (e < E) {
        int d = dst[e];
        int b = d >> BSHIFT;
        int pos = atomicAdd(&gcur[b], 1);
        part[offs[b] + pos] = ((d & (BNODES - 1)) << SRCBITS) | src[e];
    }
}

// ================= per-bucket degree -> dinv =================
__global__ void k_bucket_dinv(const int* __restrict__ part, const int* __restrict__ offs,
                              float* __restrict__ dinv, int n) {
    __shared__ int cnt[BNODES];
    int b = blockIdx.x;
    if (threadIdx.x < BNODES) cnt[threadIdx.x] = 0;
    __syncthreads();
    int beg = offs[b], end = offs[b + 1];
    for (int i = beg + threadIdx.x; i < end; i += 256)
        atomicAdd(&cnt[part[i] >> SRCBITS], 1);
    __syncthreads();
    if (threadIdx.x < BNODES) {
        int node = (b << BSHIFT) + threadIdx.x;
        if (node < n) dinv[node] = rsqrtf((float)(cnt[threadIdx.x] + 1));
    }
}

// ================= GEMM + dinv scale: g[i][c] = dinv[i] * (x @ W)[i][c] =================
template<int K>
__launch_bounds__(256)
__global__ void k_gemm_scale(const float* __restrict__ x, const float* __restrict__ W,
                             const float* __restrict__ dinv, float* __restrict__ g, int n) {
    __shared__ float sW[K * HID];
    for (int t = threadIdx.x; t < K * HID; t += 256) sW[t] = W[t];
    __syncthreads();
    const int lane = threadIdx.x & 63;
    const int rowInBlk = threadIdx.x >> 6;
    const int ROWS = 32;
    const int base = blockIdx.x * ROWS;
    for (int r = rowInBlk; r < ROWS; r += 4) {
        int i = base + r;
        if (i >= n) return;
        const float* xr = x + (size_t)i * K;
        float acc = 0.0f;
#pragma unroll
        for (int k = 0; k < K; k += 4) {
            float4 xv = *(const float4*)(xr + k);
            acc = fmaf(xv.x, sW[(k + 0) * HID + lane], acc);
            acc = fmaf(xv.y, sW[(k + 1) * HID + lane], acc);
            acc = fmaf(xv.z, sW[(k + 2) * HID + lane], acc);
            acc = fmaf(xv.w, sW[(k + 3) * HID + lane], acc);
        }
        g[(size_t)i * HID + lane] = acc * dinv[i];
    }
}

// ================= edge-parallel bucket aggregation (+ fused next GEMM) =================
// LDS acc[64][64]; one block per bucket; wave processes 8 edges at a time.
// non-LAST: out = dinv * (W^T h),  h = relu(dinv*(acc+self)+bias)
// LAST:     out = dinv*(acc+self)+bias
template<bool LAST>
__launch_bounds__(256)
__global__ void k_bucket_agg(const int* __restrict__ part, const int* __restrict__ offs,
                             const float* __restrict__ g, const float* __restrict__ dinv,
                             const float* __restrict__ bias, const float* __restrict__ Wn,
                             float* __restrict__ outp, int n) {
    __shared__ float acc[BNODES * HID];
    __shared__ float sW[LAST ? 4 : HID * HID];
    const int tid = threadIdx.x, lane = tid & 63, wv = tid >> 6;
    for (int t = tid; t < BNODES * HID; t += 256) acc[t] = 0.0f;
    if (!LAST) {
        for (int t = tid; t < HID * HID; t += 256) sW[t] = Wn[t];
    }
    __syncthreads();
    const int b = blockIdx.x;
    const int beg = offs[b], end = offs[b + 1];
    int i0 = beg + wv * 8;
    for (; i0 + 8 <= end; i0 += 32) {
        int c[8];
        float v[8];
#pragma unroll
        for (int j = 0; j < 8; ++j) c[j] = part[i0 + j];
#pragma unroll
        for (int j = 0; j < 8; ++j) v[j] = g[((size_t)(c[j] & SRCMASK)) * HID + lane];
#pragma unroll
        for (int j = 0; j < 8; ++j) atomicAdd(&acc[((c[j] >> SRCBITS) << 6) + lane], v[j]);
    }
    for (; i0 < end; ++i0) {
        int c = part[i0];
        float v = g[((size_t)(c & SRCMASK)) * HID + lane];
        atomicAdd(&acc[((c >> SRCBITS) << 6) + lane], v);
    }
    __syncthreads();
    const int nb0 = b << BSHIFT;
    const float bl = bias[lane];
    const int r0 = wv * (BNODES / 4);
    for (int r = r0; r < r0 + BNODES / 4; ++r) {
        int node = nb0 + r;
        if (node >= n) break;
        float di = dinv[node];
        float self = g[(size_t)node * HID + lane];
        float h = di * (acc[(r << 6) + lane] + self) + bl;
        if (LAST) {
            outp[(size_t)node * HID + lane] = h;
        } else {
            h = fmaxf(h, 0.0f);
            acc[(r << 6) + lane] = h;  // same-wave write, same-wave read below
            float o = 0.0f;
            const float* hr = &acc[r << 6];
#pragma unroll
            for (int k = 0; k < HID; k += 4) {
                float4 hv = *(const float4*)(hr + k);
                o = fmaf(hv.x, sW[(k + 0) * HID + lane], o);
                o = fmaf(hv.y, sW[(k + 1) * HID + lane], o);
                o = fmaf(hv.z, sW[(k + 2) * HID + lane], o);
                o = fmaf(hv.w, sW[(k + 3) * HID + lane], o);
            }
            outp[(size_t)node * HID + lane] = o * di;
        }
    }
}

// ================= link scores =================
__launch_bounds__(256)
__global__ void k_score(const int* __restrict__ ls, const int* __restrict__ ld,
                        const float* __restrict__ h, float* __restrict__ out, int EL) {
    long t = (long)blockIdx.x * 256 + threadIdx.x;
    long e = t >> 4;
    if (e >= EL) return;
    int q = (int)(t & 15);
    int s = ls[e];
    int d = ld[e];
    float4 a  = *(const float4*)(h + (size_t)s * HID + q * 4);
    float4 bb = *(const float4*)(h + (size_t)d * HID + q * 4);
    float p = a.x * bb.x + a.y * bb.y + a.z * bb.z + a.w * bb.w;
    p += __shfl_xor(p, 1);
    p += __shfl_xor(p, 2);
    p += __shfl_xor(p, 4);
    p += __shfl_xor(p, 8);
    if (q == 0) out[e] = 1.0f / (1.0f + __expf(-p));
}

// ================= fallback path: proven r3 ELL kernels =================
__global__ void k_ell_fill(const int* __restrict__ src, const int* __restrict__ dst,
                           int* __restrict__ cur, int* __restrict__ ell, int E) {
    int e = blockIdx.x * blockDim.x + threadIdx.x;
    if (e < E) {
        int d = dst[e];
        int p = atomicAdd(&cur[d], 1);
        if (p < ELLW) ell[(size_t)d * ELLW + p] = src[e];
    }
}
__global__ void k_dinv_from_deg(const int* __restrict__ deg, float* __restrict__ dinv, int n) {
    int i = blockIdx.x * blockDim.x + threadIdx.x;
    if (i < n) dinv[i] = rsqrtf((float)(deg[i] + 1));
}
__launch_bounds__(256)
__global__ void k_agg_gemm(const int* __restrict__ deg, const int* __restrict__ ell,
                           const float* __restrict__ g, const float* __restrict__ dinv,
                           const float* __restrict__ bias, const float* __restrict__ Wn,
                           float* __restrict__ gout, int n) {
    __shared__ float sW[HID * HID];
    __shared__ float sH[4][HID];
    for (int t = threadIdx.x; t < HID * HID; t += 256) sW[t] = Wn[t];
    const int wv = threadIdx.x >> 6;
    const int lane = threadIdx.x & 63;
    const int node = blockIdx.x * 4 + wv;
    if (node < n) {
        int dg = deg[node];
        int len = dg < ELLW ? dg : ELLW;
        const int* row = ell + (size_t)node * ELLW;
        float acc = g[(size_t)node * HID + lane];
        int j = 0;
        for (; j + 4 <= len; j += 4) {
            int s0 = row[j], s1 = row[j + 1], s2 = row[j + 2], s3 = row[j + 3];
            acc += (g[(size_t)s0 * HID + lane] + g[(size_t)s1 * HID + lane]) +
                   (g[(size_t)s2 * HID + lane] + g[(size_t)s3 * HID + lane]);
        }
        for (; j < len; ++j) acc += g[(size_t)row[j] * HID + lane];
        float h = fmaxf(dinv[node] * acc + bias[lane], 0.0f);
        sH[wv][lane] = h;
    }
    __syncthreads();
    if (node < n) {
        const float* hr = sH[wv];
        float o = 0.0f;
#pragma unroll
        for (int k = 0; k < HID; k += 4) {
            o = fmaf(hr[k + 0], sW[(k + 0) * HID + lane], o);
            o = fmaf(hr[k + 1], sW[(k + 1) * HID + lane], o);
            o = fmaf(hr[k + 2], sW[(k + 2) * HID + lane], o);
            o = fmaf(hr[k + 3], sW[(k + 3) * HID + lane], o);
        }
        gout[(size_t)node * HID + lane] = o * dinv[node];
    }
}
__launch_bounds__(256)
__global__ void k_aggregate_ell(const int* __restrict__ deg, const int* __restrict__ ell,
                                const float* __restrict__ g, float* __restrict__ out,
                                const float* __restrict__ dinv, const float* __restrict__ b,
                                int n) {
    int node = (int)(((long)blockIdx.x * 256 + threadIdx.x) >> 6);
    int lane = threadIdx.x & 63;
    if (node >= n) return;
    int dg = deg[node];
    int len = dg < ELLW ? dg : ELLW;
    const int* row = ell + (size_t)node * ELLW;
    float acc = g[(size_t)node * HID + lane];
    int j = 0;
    for (; j + 4 <= len; j += 4) {
        int s0 = row[j], s1 = row[j + 1], s2 = row[j + 2], s3 = row[j + 3];
        acc += (g[(size_t)s0 * HID + lane] + g[(size_t)s1 * HID + lane]) +
               (g[(size_t)s2 * HID + lane] + g[(size_t)s3 * HID + lane]);
    }
    for (; j < len; ++j) acc += g[(size_t)row[j] * HID + lane];
    out[(size_t)node * HID + lane] = dinv[node] * acc + b[lane];
}

static inline size_t alignup(size_t v) { return (v + 255) & ~(size_t)255; }

extern "C" void kernel_launch(void* const* d_in, const int* in_sizes, int n_in,
                              void* d_out, int out_size, void* d_ws, size_t ws_size,
                              hipStream_t stream) {
    const float* x  = (const float*)d_in[0];
    const float* W1 = (const float*)d_in[1];
    const float* b1 = (const float*)d_in[2];
    const float* W2 = (const float*)d_in[3];
    const float* b2 = (const float*)d_in[4];
    const float* W3 = (const float*)d_in[5];
    const float* b3 = (const float*)d_in[6];
    const int* ei  = (const int*)d_in[7];
    const int* eli = (const int*)d_in[8];

    const int n  = in_sizes[0] / 128;
    const int E  = in_sizes[7] / 2;
    const int EL = in_sizes[8] / 2;
    float* out = (float*)d_out;

    const int* esrc = ei;
    const int* edst = ei + E;

    const long nh = (long)n * HID;
    const int nBlk  = (n + 255) / 256;
    const int eBlk  = (E + 255) / 256;
    const int gBlk  = (n + 31) / 32;
    const int scBlk = (int)(((long)EL * 16 + 255) / 256);
    const int nb = (n + BNODES - 1) >> BSHIFT;

    // -------- workspace layout (partitioned path) --------
    size_t o = 0;
    char* ws = (char*)d_ws;
    int*   bcnt = (int*)(ws + o);   o += alignup((size_t)MAXBUCK * 4);      // counts, then gcur zeroed together
    int*   gcur = (int*)(ws + o);   o += alignup((size_t)MAXBUCK * 4);
    int*   boffs = (int*)(ws + o);  o += alignup((size_t)(MAXBUCK + 1) * 4);
    float* dinv = (float*)(ws + o); o += alignup((size_t)n * 4);
    int*   part = (int*)(ws + o);   o += alignup((size_t)E * 4);
    float* bufA = (float*)(ws + o); o += alignup(nh * 4);
    float* bufB = (float*)(ws + o); o += alignup(nh * 4);
    const size_t need_part = o;

    if (n <= (1 << SRCBITS) && nb <= MAXBUCK && ws_size >= need_part) {
        // ---- build partitioned edge list ----
        k_zero_int<<<(2 * MAXBUCK + 255) / 256, 256, 0, stream>>>(bcnt, 2 * MAXBUCK);  // bcnt+gcur contiguous
        k_hist<<<256, 256, 0, stream>>>(edst, bcnt, E, nb);
        k_scan2<<<1, 1024, 0, stream>>>(bcnt, boffs, nb);
        k_part_scatter<<<eBlk, 256, 0, stream>>>(esrc, edst, boffs, gcur, part, E);
        k_bucket_dinv<<<nb, 256, 0, stream>>>(part, boffs, dinv, n);

        // ---- layers ----
        k_gemm_scale<128><<<gBlk, 256, 0, stream>>>(x, W1, dinv, bufA, n);                     // g1
        k_bucket_agg<false><<<nb, 256, 0, stream>>>(part, boffs, bufA, dinv, b1, W2, bufB, n); // g2
        k_bucket_agg<false><<<nb, 256, 0, stream>>>(part, boffs, bufB, dinv, b2, W3, bufA, n); // g3
        k_bucket_agg<true ><<<nb, 256, 0, stream>>>(part, boffs, bufA, dinv, b3, W3, bufB, n); // h3

        k_score<<<scBlk, 256, 0, stream>>>(eli, eli + EL, bufB, out, EL);
    } else {
        // -------- fallback: proven r3 ELL path --------
        size_t o2 = 0;
        int*   cur   = (int*)(ws + o2);   o2 += alignup((size_t)n * 4);
        float* dinv2 = (float*)(ws + o2); o2 += alignup((size_t)n * 4);
        int*   ell   = (int*)(ws + o2);   o2 += alignup((size_t)n * ELLW * 4);
        float* fA    = (float*)(ws + o2); o2 += alignup(nh * 4);
        float* fB    = (float*)(ws + o2); o2 += alignup(nh * 4);
        const int aBlk = (n + 3) / 4;

        k_zero_int<<<nBlk, 256, 0, stream>>>(cur, n);
        k_ell_fill<<<eBlk, 256, 0, stream>>>(esrc, edst, cur, ell, E);
        k_dinv_from_deg<<<nBlk, 256, 0, stream>>>(cur, dinv2, n);

        k_gemm_scale<128><<<gBlk, 256, 0, stream>>>(x, W1, dinv2, fA, n);
        k_agg_gemm<<<aBlk, 256, 0, stream>>>(cur, ell, fA, dinv2, b1, W2, fB, n);
        k_agg_gemm<<<aBlk, 256, 0, stream>>>(cur, ell, fB, dinv2, b2, W3, fA, n);
        k_aggregate_ell<<<aBlk, 256, 0, stream>>>(cur, ell, fA, fB, dinv2, b3, n);

        k_score<<<scBlk, 256, 0, stream>>>(eli, eli + EL, fB, out, EL);
    }
}

// Round 5
// 819.322 us; speedup vs baseline: 5.2172x; 5.2172x over previous
//
#include <hip/hip_runtime.h>
#include <math.h>

#define HID 64
#define BSH 8                      // 256 nodes per bucket
#define BN 256
#define SRCBITS 17
#define SRCMASK ((1 << SRCBITS) - 1)
#define PB 64                      // partition blocks
#define MAXNB 512                  // max buckets (n <= 131072)
#define ELLW 96

// ================= small utility =================
__global__ void k_zero_int(int* __restrict__ p, int n) {
    int i = blockIdx.x * blockDim.x + threadIdx.x;
    if (i < n) p[i] = 0;
}

// ================= P1: per-block bucket histogram =================
__global__ void k_hist(const int* __restrict__ dst, int* __restrict__ table,
                       int E, int nb, int chunk) {
    __shared__ int lh[MAXNB];
    for (int t = threadIdx.x; t < nb; t += 256) lh[t] = 0;
    __syncthreads();
    int beg = blockIdx.x * chunk;
    int end = beg + chunk; if (end > E) end = E;
    for (int e = beg + threadIdx.x; e < end; e += 256)
        atomicAdd(&lh[dst[e] >> BSH], 1);
    __syncthreads();
    for (int t = threadIdx.x; t < nb; t += 256)
        table[t * PB + blockIdx.x] = lh[t];
}

// ================= P2: exclusive scan of table (bucket-major), single block =================
__global__ void k_scanL(const int* __restrict__ in, int* __restrict__ out, int L) {
    __shared__ int lds[1024];
    __shared__ int carry;
    if (threadIdx.x == 0) carry = 0;
    __syncthreads();
    for (int base = 0; base < L; base += 1024) {
        int i = base + threadIdx.x;
        int v = (i < L) ? in[i] : 0;
        lds[threadIdx.x] = v;
        __syncthreads();
        for (int off = 1; off < 1024; off <<= 1) {
            int t = (threadIdx.x >= off) ? lds[threadIdx.x - off] : 0;
            __syncthreads();
            lds[threadIdx.x] += t;
            __syncthreads();
        }
        if (i < L) out[i] = lds[threadIdx.x] - v + carry;
        __syncthreads();
        if (threadIdx.x == 0) carry += lds[1023];
        __syncthreads();
    }
}

// ================= P3: partition scatter, block-exclusive cursors (no global atomics) =================
__global__ void k_pscatter(const int* __restrict__ src, const int* __restrict__ dst,
                           const int* __restrict__ excl, int* __restrict__ part,
                           int E, int nb, int chunk) {
    __shared__ int cur[MAXNB];
    for (int t = threadIdx.x; t < nb; t += 256) cur[t] = excl[t * PB + blockIdx.x];
    __syncthreads();
    int beg = blockIdx.x * chunk;
    int end = beg + chunk; if (end > E) end = E;
    for (int e = beg + threadIdx.x; e < end; e += 256) {
        int d = dst[e];
        int bu = d >> BSH;
        int pos = atomicAdd(&cur[bu], 1);
        part[pos] = ((d & (BN - 1)) << SRCBITS) | src[e];
    }
}

// ================= P4: per-bucket ELL fill + degree + dinv =================
__global__ void k_bell(const int* __restrict__ part, const int* __restrict__ excl,
                       int* __restrict__ ell, int* __restrict__ deg,
                       float* __restrict__ dinv, int E, int nb, int n) {
    __shared__ int cnt[BN];
    int b = blockIdx.x;
    for (int t = threadIdx.x; t < BN; t += 256) cnt[t] = 0;
    __syncthreads();
    int beg = excl[b * PB];
    int end = (b == nb - 1) ? E : excl[(b + 1) * PB];
    for (int i = beg + threadIdx.x; i < end; i += 256) {
        int c = part[i];
        int dl = c >> SRCBITS;
        int p = atomicAdd(&cnt[dl], 1);
        if (p < ELLW) ell[(size_t)((b << BSH) + dl) * ELLW + p] = c & SRCMASK;
    }
    __syncthreads();
    for (int t = threadIdx.x; t < BN; t += 256) {
        int node = (b << BSH) + t;
        if (node < n) {
            int dgv = cnt[t];
            deg[node] = dgv;
            dinv[node] = rsqrtf((float)(dgv + 1));
        }
    }
}

// ================= GEMM + dinv scale: g[i][c] = dinv[i] * (x @ W)[i][c] =================
template<int K>
__launch_bounds__(256)
__global__ void k_gemm_scale(const float* __restrict__ x, const float* __restrict__ W,
                             const float* __restrict__ dinv, float* __restrict__ g, int n) {
    __shared__ float sW[K * HID];
    for (int t = threadIdx.x; t < K * HID; t += 256) sW[t] = W[t];
    __syncthreads();
    const int lane = threadIdx.x & 63;
    const int rowInBlk = threadIdx.x >> 6;
    const int ROWS = 32;
    const int base = blockIdx.x * ROWS;
    for (int r = rowInBlk; r < ROWS; r += 4) {
        int i = base + r;
        if (i >= n) return;
        const float* xr = x + (size_t)i * K;
        float acc = 0.0f;
#pragma unroll
        for (int k = 0; k < K; k += 4) {
            float4 xv = *(const float4*)(xr + k);
            acc = fmaf(xv.x, sW[(k + 0) * HID + lane], acc);
            acc = fmaf(xv.y, sW[(k + 1) * HID + lane], acc);
            acc = fmaf(xv.z, sW[(k + 2) * HID + lane], acc);
            acc = fmaf(xv.w, sW[(k + 3) * HID + lane], acc);
        }
        g[(size_t)i * HID + lane] = acc * dinv[i];
    }
}

// ================= fused aggregate + next-layer GEMM (node-parallel, proven r3) =================
__launch_bounds__(256)
__global__ void k_agg_gemm(const int* __restrict__ deg, const int* __restrict__ ell,
                           const float* __restrict__ g, const float* __restrict__ dinv,
                           const float* __restrict__ bias, const float* __restrict__ Wn,
                           float* __restrict__ gout, int n) {
    __shared__ float sW[HID * HID];
    __shared__ float sH[4][HID];
    for (int t = threadIdx.x; t < HID * HID; t += 256) sW[t] = Wn[t];
    const int wv = threadIdx.x >> 6;
    const int lane = threadIdx.x & 63;
    const int node = blockIdx.x * 4 + wv;
    if (node < n) {
        int dg = deg[node];
        int len = dg < ELLW ? dg : ELLW;
        const int* row = ell + (size_t)node * ELLW;
        float acc = g[(size_t)node * HID + lane];
        int j = 0;
        for (; j + 4 <= len; j += 4) {
            int s0 = row[j], s1 = row[j + 1], s2 = row[j + 2], s3 = row[j + 3];
            acc += (g[(size_t)s0 * HID + lane] + g[(size_t)s1 * HID + lane]) +
                   (g[(size_t)s2 * HID + lane] + g[(size_t)s3 * HID + lane]);
        }
        for (; j < len; ++j) acc += g[(size_t)row[j] * HID + lane];
        float h = fmaxf(dinv[node] * acc + bias[lane], 0.0f);
        sH[wv][lane] = h;
    }
    __syncthreads();
    if (node < n) {
        const float* hr = sH[wv];
        float o = 0.0f;
#pragma unroll
        for (int k = 0; k < HID; k += 4) {
            o = fmaf(hr[k + 0], sW[(k + 0) * HID + lane], o);
            o = fmaf(hr[k + 1], sW[(k + 1) * HID + lane], o);
            o = fmaf(hr[k + 2], sW[(k + 2) * HID + lane], o);
            o = fmaf(hr[k + 3], sW[(k + 3) * HID + lane], o);
        }
        gout[(size_t)node * HID + lane] = o * dinv[node];
    }
}

// ================= final aggregate (layer 3) =================
__launch_bounds__(256)
__global__ void k_aggregate_ell(const int* __restrict__ deg, const int* __restrict__ ell,
                                const float* __restrict__ g, float* __restrict__ out,
                                const float* __restrict__ dinv, const float* __restrict__ b,
                                int n) {
    int node = (int)(((long)blockIdx.x * 256 + threadIdx.x) >> 6);
    int lane = threadIdx.x & 63;
    if (node >= n) return;
    int dg = deg[node];
    int len = dg < ELLW ? dg : ELLW;
    const int* row = ell + (size_t)node * ELLW;
    float acc = g[(size_t)node * HID + lane];
    int j = 0;
    for (; j + 4 <= len; j += 4) {
        int s0 = row[j], s1 = row[j + 1], s2 = row[j + 2], s3 = row[j + 3];
        acc += (g[(size_t)s0 * HID + lane] + g[(size_t)s1 * HID + lane]) +
               (g[(size_t)s2 * HID + lane] + g[(size_t)s3 * HID + lane]);
    }
    for (; j < len; ++j) acc += g[(size_t)row[j] * HID + lane];
    out[(size_t)node * HID + lane] = dinv[node] * acc + b[lane];
}

// ================= link scores =================
__launch_bounds__(256)
__global__ void k_score(const int* __restrict__ ls, const int* __restrict__ ld,
                        const float* __restrict__ h, float* __restrict__ out, int EL) {
    long t = (long)blockIdx.x * 256 + threadIdx.x;
    long e = t >> 4;
    if (e >= EL) return;
    int q = (int)(t & 15);
    int s = ls[e];
    int d = ld[e];
    float4 a  = *(const float4*)(h + (size_t)s * HID + q * 4);
    float4 bb = *(const float4*)(h + (size_t)d * HID + q * 4);
    float p = a.x * bb.x + a.y * bb.y + a.z * bb.z + a.w * bb.w;
    p += __shfl_xor(p, 1);
    p += __shfl_xor(p, 2);
    p += __shfl_xor(p, 4);
    p += __shfl_xor(p, 8);
    if (q == 0) out[e] = 1.0f / (1.0f + __expf(-p));
}

// ================= fallback: proven r3 single-pass ELL build =================
__global__ void k_ell_fill(const int* __restrict__ src, const int* __restrict__ dst,
                           int* __restrict__ cur, int* __restrict__ ell, int E) {
    int e = blockIdx.x * blockDim.x + threadIdx.x;
    if (e < E) {
        int d = dst[e];
        int p = atomicAdd(&cur[d], 1);
        if (p < ELLW) ell[(size_t)d * ELLW + p] = src[e];
    }
}
__global__ void k_dinv_from_deg(const int* __restrict__ deg, float* __restrict__ dinv, int n) {
    int i = blockIdx.x * blockDim.x + threadIdx.x;
    if (i < n) dinv[i] = rsqrtf((float)(deg[i] + 1));
}

static inline size_t alignup(size_t v) { return (v + 255) & ~(size_t)255; }

extern "C" void kernel_launch(void* const* d_in, const int* in_sizes, int n_in,
                              void* d_out, int out_size, void* d_ws, size_t ws_size,
                              hipStream_t stream) {
    const float* x  = (const float*)d_in[0];
    const float* W1 = (const float*)d_in[1];
    const float* b1 = (const float*)d_in[2];
    const float* W2 = (const float*)d_in[3];
    const float* b2 = (const float*)d_in[4];
    const float* W3 = (const float*)d_in[5];
    const float* b3 = (const float*)d_in[6];
    const int* ei  = (const int*)d_in[7];
    const int* eli = (const int*)d_in[8];

    const int n  = in_sizes[0] / 128;
    const int E  = in_sizes[7] / 2;
    const int EL = in_sizes[8] / 2;
    float* out = (float*)d_out;

    const int* esrc = ei;
    const int* edst = ei + E;

    const long nh = (long)n * HID;
    const int nBlk  = (n + 255) / 256;
    const int eBlk  = (E + 255) / 256;
    const int gBlk  = (n + 31) / 32;
    const int aBlk  = (n + 3) / 4;
    const int scBlk = (int)(((long)EL * 16 + 255) / 256);
    const int nb = (n + BN - 1) >> BSH;
    const int chunk = (E + PB - 1) / PB;

    // -------- workspace layout (partitioned-build path) --------
    size_t o = 0;
    char* ws = (char*)d_ws;
    int*   table = (int*)(ws + o); o += alignup((size_t)MAXNB * PB * 4);
    int*   excl  = (int*)(ws + o); o += alignup((size_t)MAXNB * PB * 4);
    int*   deg   = (int*)(ws + o); o += alignup((size_t)n * 4);
    float* dinv  = (float*)(ws + o); o += alignup((size_t)n * 4);
    int*   ell   = (int*)(ws + o); o += alignup((size_t)n * ELLW * 4);
    float* bufA  = (float*)(ws + o); o += alignup(nh * 4);
    float* bufB  = (float*)(ws + o); o += alignup(nh * 4);
    const size_t need_part = o;
    int* part = (int*)bufA;  // part (E ints = 12.8MB) dead before gemm writes bufA (25.6MB)

    if (n <= (1 << SRCBITS) && nb <= MAXNB && (long)E * 4 <= nh * 4 && ws_size >= need_part) {
        // ---- build: contention-free two-pass partition + per-bucket ELL ----
        k_hist<<<PB, 256, 0, stream>>>(edst, table, E, nb, chunk);
        k_scanL<<<1, 1024, 0, stream>>>(table, excl, nb * PB);
        k_pscatter<<<PB, 256, 0, stream>>>(esrc, edst, excl, part, E, nb, chunk);
        k_bell<<<nb, 256, 0, stream>>>(part, excl, ell, deg, dinv, E, nb, n);

        // ---- layers (proven r3 structure) ----
        k_gemm_scale<128><<<gBlk, 256, 0, stream>>>(x, W1, dinv, bufA, n);          // g1 (kills part)
        k_agg_gemm<<<aBlk, 256, 0, stream>>>(deg, ell, bufA, dinv, b1, W2, bufB, n); // g2
        k_agg_gemm<<<aBlk, 256, 0, stream>>>(deg, ell, bufB, dinv, b2, W3, bufA, n); // g3
        k_aggregate_ell<<<aBlk, 256, 0, stream>>>(deg, ell, bufA, bufB, dinv, b3, n); // h3

        k_score<<<scBlk, 256, 0, stream>>>(eli, eli + EL, bufB, out, EL);
    } else {
        // -------- fallback: proven r3 single-pass ELL path --------
        size_t o2 = 0;
        int*   cur   = (int*)(ws + o2);   o2 += alignup((size_t)n * 4);
        float* dinv2 = (float*)(ws + o2); o2 += alignup((size_t)n * 4);
        int*   ell2  = (int*)(ws + o2);   o2 += alignup((size_t)n * ELLW * 4);
        float* fA    = (float*)(ws + o2); o2 += alignup(nh * 4);
        float* fB    = (float*)(ws + o2); o2 += alignup(nh * 4);

        k_zero_int<<<nBlk, 256, 0, stream>>>(cur, n);
        k_ell_fill<<<eBlk, 256, 0, stream>>>(esrc, edst, cur, ell2, E);
        k_dinv_from_deg<<<nBlk, 256, 0, stream>>>(cur, dinv2, n);

        k_gemm_scale<128><<<gBlk, 256, 0, stream>>>(x, W1, dinv2, fA, n);
        k_agg_gemm<<<aBlk, 256, 0, stream>>>(cur, ell2, fA, dinv2, b1, W2, fB, n);
        k_agg_gemm<<<aBlk, 256, 0, stream>>>(cur, ell2, fB, dinv2, b2, W3, fA, n);
        k_aggregate_ell<<<aBlk, 256, 0, stream>>>(cur, ell2, fA, fB, dinv2, b3, n);

        k_score<<<scBlk, 256, 0, stream>>>(eli, eli + EL, fB, out, EL);
    }
}

// Round 6
// 653.158 us; speedup vs baseline: 6.5445x; 1.2544x over previous
//
#include <hip/hip_runtime.h>
#include <math.h>

#define HID 64
#define BSH 8                      // 256 nodes per bucket
#define BN 256
#define SRCBITS 17
#define SRCMASK ((1 << SRCBITS) - 1)
#define PB 512                     // partition chunks (one block each)
#define MAXNB 512                  // max buckets (n <= 131072)
#define ELLW 96

// ================= small utility =================
__global__ void k_zero_int(int* __restrict__ p, int n) {
    int i = blockIdx.x * blockDim.x + threadIdx.x;
    if (i < n) p[i] = 0;
}

// ================= P1: per-chunk bucket histogram -> table[bu*PB + chunk] =================
__global__ void k_hist(const int* __restrict__ dst, int* __restrict__ table,
                       int E, int nb, int chunk) {
    __shared__ int lh[MAXNB];
    for (int t = threadIdx.x; t < nb; t += 256) lh[t] = 0;
    __syncthreads();
    int beg = blockIdx.x * chunk;
    int end = beg + chunk; if (end > E) end = E;
    for (int e = beg + threadIdx.x; e < end; e += 256)
        atomicAdd(&lh[dst[e] >> BSH], 1);
    __syncthreads();
    for (int t = threadIdx.x; t < nb; t += 256)
        table[t * PB + blockIdx.x] = lh[t];
}

// ================= P2a: per-bucket exclusive scan across chunks (in-place), rowsum out =================
__global__ void k_scanA(int* __restrict__ table, int* __restrict__ rowsum) {
    __shared__ int lds[PB];
    const int bu = blockIdx.x;
    const int t = threadIdx.x;  // PB threads
    int v = table[bu * PB + t];
    lds[t] = v;
    __syncthreads();
    for (int off = 1; off < PB; off <<= 1) {
        int u = (t >= off) ? lds[t - off] : 0;
        __syncthreads();
        lds[t] += u;
        __syncthreads();
    }
    table[bu * PB + t] = lds[t] - v;  // exclusive within bucket row
    if (t == PB - 1) rowsum[bu] = lds[t];
}

// ================= P2b: exclusive scan of bucket totals (single block) =================
__global__ void k_scanB(int* __restrict__ rowsum, int nb) {
    __shared__ int lds[PB];
    const int t = threadIdx.x;  // PB threads
    int v = (t < nb) ? rowsum[t] : 0;
    lds[t] = v;
    __syncthreads();
    for (int off = 1; off < PB; off <<= 1) {
        int u = (t >= off) ? lds[t - off] : 0;
        __syncthreads();
        lds[t] += u;
        __syncthreads();
    }
    if (t < nb) rowsum[t] = lds[t] - v;
}

// ================= P2c: add bucket base to each row entry =================
__global__ void k_scanC(int* __restrict__ table, const int* __restrict__ rowsum, int L) {
    int i = blockIdx.x * 256 + threadIdx.x;
    if (i < L) table[i] += rowsum[i >> 9];  // i / PB, PB=512
}

// ================= P3: partition scatter, chunk-exclusive cursors =================
__global__ void k_pscatter(const int* __restrict__ src, const int* __restrict__ dst,
                           const int* __restrict__ excl, int* __restrict__ part,
                           int E, int nb, int chunk) {
    __shared__ int cur[MAXNB];
    for (int t = threadIdx.x; t < nb; t += 256) cur[t] = excl[t * PB + blockIdx.x];
    __syncthreads();
    int beg = blockIdx.x * chunk;
    int end = beg + chunk; if (end > E) end = E;
    for (int e = beg + threadIdx.x; e < end; e += 256) {
        int d = dst[e];
        int bu = d >> BSH;
        int pos = atomicAdd(&cur[bu], 1);
        part[pos] = ((d & (BN - 1)) << SRCBITS) | src[e];
    }
}

// ================= P4: per-bucket ELL fill + degree + dinv =================
__global__ void k_bell(const int* __restrict__ part, const int* __restrict__ excl,
                       int* __restrict__ ell, int* __restrict__ deg,
                       float* __restrict__ dinv, int E, int nb, int n) {
    __shared__ int cnt[BN];
    int b = blockIdx.x;
    for (int t = threadIdx.x; t < BN; t += 256) cnt[t] = 0;
    __syncthreads();
    int beg = excl[b * PB];
    int end = (b == nb - 1) ? E : excl[(b + 1) * PB];
    for (int i = beg + threadIdx.x; i < end; i += 256) {
        int c = part[i];
        int dl = c >> SRCBITS;
        int p = atomicAdd(&cnt[dl], 1);
        if (p < ELLW) ell[(size_t)((b << BSH) + dl) * ELLW + p] = c & SRCMASK;
    }
    __syncthreads();
    for (int t = threadIdx.x; t < BN; t += 256) {
        int node = (b << BSH) + t;
        if (node < n) {
            int dgv = cnt[t];
            deg[node] = dgv;
            dinv[node] = rsqrtf((float)(dgv + 1));
        }
    }
}

// ================= GEMM + dinv scale: g[i][c] = dinv[i] * (x @ W)[i][c] =================
template<int K>
__launch_bounds__(256)
__global__ void k_gemm_scale(const float* __restrict__ x, const float* __restrict__ W,
                             const float* __restrict__ dinv, float* __restrict__ g, int n) {
    __shared__ float sW[K * HID];
    for (int t = threadIdx.x; t < K * HID; t += 256) sW[t] = W[t];
    __syncthreads();
    const int lane = threadIdx.x & 63;
    const int rowInBlk = threadIdx.x >> 6;
    const int ROWS = 32;
    const int base = blockIdx.x * ROWS;
    for (int r = rowInBlk; r < ROWS; r += 4) {
        int i = base + r;
        if (i >= n) return;
        const float* xr = x + (size_t)i * K;
        float acc = 0.0f;
#pragma unroll
        for (int k = 0; k < K; k += 4) {
            float4 xv = *(const float4*)(xr + k);
            acc = fmaf(xv.x, sW[(k + 0) * HID + lane], acc);
            acc = fmaf(xv.y, sW[(k + 1) * HID + lane], acc);
            acc = fmaf(xv.z, sW[(k + 2) * HID + lane], acc);
            acc = fmaf(xv.w, sW[(k + 3) * HID + lane], acc);
        }
        g[(size_t)i * HID + lane] = acc * dinv[i];
    }
}

// ================= fused aggregate + next-layer GEMM (node-parallel, proven r3) =================
__launch_bounds__(256)
__global__ void k_agg_gemm(const int* __restrict__ deg, const int* __restrict__ ell,
                           const float* __restrict__ g, const float* __restrict__ dinv,
                           const float* __restrict__ bias, const float* __restrict__ Wn,
                           float* __restrict__ gout, int n) {
    __shared__ float sW[HID * HID];
    __shared__ float sH[4][HID];
    for (int t = threadIdx.x; t < HID * HID; t += 256) sW[t] = Wn[t];
    const int wv = threadIdx.x >> 6;
    const int lane = threadIdx.x & 63;
    const int node = blockIdx.x * 4 + wv;
    if (node < n) {
        int dg = deg[node];
        int len = dg < ELLW ? dg : ELLW;
        const int* row = ell + (size_t)node * ELLW;
        float acc = g[(size_t)node * HID + lane];
        int j = 0;
        for (; j + 4 <= len; j += 4) {
            int s0 = row[j], s1 = row[j + 1], s2 = row[j + 2], s3 = row[j + 3];
            acc += (g[(size_t)s0 * HID + lane] + g[(size_t)s1 * HID + lane]) +
                   (g[(size_t)s2 * HID + lane] + g[(size_t)s3 * HID + lane]);
        }
        for (; j < len; ++j) acc += g[(size_t)row[j] * HID + lane];
        float h = fmaxf(dinv[node] * acc + bias[lane], 0.0f);
        sH[wv][lane] = h;
    }
    __syncthreads();
    if (node < n) {
        const float* hr = sH[wv];
        float o = 0.0f;
#pragma unroll
        for (int k = 0; k < HID; k += 4) {
            o = fmaf(hr[k + 0], sW[(k + 0) * HID + lane], o);
            o = fmaf(hr[k + 1], sW[(k + 1) * HID + lane], o);
            o = fmaf(hr[k + 2], sW[(k + 2) * HID + lane], o);
            o = fmaf(hr[k + 3], sW[(k + 3) * HID + lane], o);
        }
        gout[(size_t)node * HID + lane] = o * dinv[node];
    }
}

// ================= final aggregate (layer 3) =================
__launch_bounds__(256)
__global__ void k_aggregate_ell(const int* __restrict__ deg, const int* __restrict__ ell,
                                const float* __restrict__ g, float* __restrict__ out,
                                const float* __restrict__ dinv, const float* __restrict__ b,
                                int n) {
    int node = (int)(((long)blockIdx.x * 256 + threadIdx.x) >> 6);
    int lane = threadIdx.x & 63;
    if (node >= n) return;
    int dg = deg[node];
    int len = dg < ELLW ? dg : ELLW;
    const int* row = ell + (size_t)node * ELLW;
    float acc = g[(size_t)node * HID + lane];
    int j = 0;
    for (; j + 4 <= len; j += 4) {
        int s0 = row[j], s1 = row[j + 1], s2 = row[j + 2], s3 = row[j + 3];
        acc += (g[(size_t)s0 * HID + lane] + g[(size_t)s1 * HID + lane]) +
               (g[(size_t)s2 * HID + lane] + g[(size_t)s3 * HID + lane]);
    }
    for (; j < len; ++j) acc += g[(size_t)row[j] * HID + lane];
    out[(size_t)node * HID + lane] = dinv[node] * acc + b[lane];
}

// ================= link scores =================
__launch_bounds__(256)
__global__ void k_score(const int* __restrict__ ls, const int* __restrict__ ld,
                        const float* __restrict__ h, float* __restrict__ out, int EL) {
    long t = (long)blockIdx.x * 256 + threadIdx.x;
    long e = t >> 4;
    if (e >= EL) return;
    int q = (int)(t & 15);
    int s = ls[e];
    int d = ld[e];
    float4 a  = *(const float4*)(h + (size_t)s * HID + q * 4);
    float4 bb = *(const float4*)(h + (size_t)d * HID + q * 4);
    float p = a.x * bb.x + a.y * bb.y + a.z * bb.z + a.w * bb.w;
    p += __shfl_xor(p, 1);
    p += __shfl_xor(p, 2);
    p += __shfl_xor(p, 4);
    p += __shfl_xor(p, 8);
    if (q == 0) out[e] = 1.0f / (1.0f + __expf(-p));
}

// ================= fallback: proven r3 single-pass ELL build =================
__global__ void k_ell_fill(const int* __restrict__ src, const int* __restrict__ dst,
                           int* __restrict__ cur, int* __restrict__ ell, int E) {
    int e = blockIdx.x * blockDim.x + threadIdx.x;
    if (e < E) {
        int d = dst[e];
        int p = atomicAdd(&cur[d], 1);
        if (p < ELLW) ell[(size_t)d * ELLW + p] = src[e];
    }
}
__global__ void k_dinv_from_deg(const int* __restrict__ deg, float* __restrict__ dinv, int n) {
    int i = blockIdx.x * blockDim.x + threadIdx.x;
    if (i < n) dinv[i] = rsqrtf((float)(deg[i] + 1));
}

static inline size_t alignup(size_t v) { return (v + 255) & ~(size_t)255; }

extern "C" void kernel_launch(void* const* d_in, const int* in_sizes, int n_in,
                              void* d_out, int out_size, void* d_ws, size_t ws_size,
                              hipStream_t stream) {
    const float* x  = (const float*)d_in[0];
    const float* W1 = (const float*)d_in[1];
    const float* b1 = (const float*)d_in[2];
    const float* W2 = (const float*)d_in[3];
    const float* b2 = (const float*)d_in[4];
    const float* W3 = (const float*)d_in[5];
    const float* b3 = (const float*)d_in[6];
    const int* ei  = (const int*)d_in[7];
    const int* eli = (const int*)d_in[8];

    const int n  = in_sizes[0] / 128;
    const int E  = in_sizes[7] / 2;
    const int EL = in_sizes[8] / 2;
    float* out = (float*)d_out;

    const int* esrc = ei;
    const int* edst = ei + E;

    const long nh = (long)n * HID;
    const int nBlk  = (n + 255) / 256;
    const int eBlk  = (E + 255) / 256;
    const int gBlk  = (n + 31) / 32;
    const int aBlk  = (n + 3) / 4;
    const int scBlk = (int)(((long)EL * 16 + 255) / 256);
    const int nb = (n + BN - 1) >> BSH;
    const int chunk = (E + PB - 1) / PB;

    // -------- workspace layout (partitioned-build path) --------
    size_t o = 0;
    char* ws = (char*)d_ws;
    int*   table  = (int*)(ws + o); o += alignup((size_t)MAXNB * PB * 4);
    int*   rowsum = (int*)(ws + o); o += alignup((size_t)MAXNB * 4);
    int*   deg    = (int*)(ws + o); o += alignup((size_t)n * 4);
    float* dinv   = (float*)(ws + o); o += alignup((size_t)n * 4);
    int*   ell    = (int*)(ws + o); o += alignup((size_t)n * ELLW * 4);
    float* bufA   = (float*)(ws + o); o += alignup(nh * 4);
    float* bufB   = (float*)(ws + o); o += alignup(nh * 4);
    const size_t need_part = o;
    int* part = (int*)bufA;  // part (E ints) dead before gemm writes bufA

    if (n <= (1 << SRCBITS) && nb <= MAXNB && (long)E * 4 <= nh * 4 && ws_size >= need_part) {
        // ---- build: contention-free two-pass partition + per-bucket ELL ----
        k_hist<<<PB, 256, 0, stream>>>(edst, table, E, nb, chunk);
        k_scanA<<<nb, PB, 0, stream>>>(table, rowsum);
        k_scanB<<<1, PB, 0, stream>>>(rowsum, nb);
        k_scanC<<<(nb * PB + 255) / 256, 256, 0, stream>>>(table, rowsum, nb * PB);
        k_pscatter<<<PB, 256, 0, stream>>>(esrc, edst, table, part, E, nb, chunk);
        k_bell<<<nb, 256, 0, stream>>>(part, table, ell, deg, dinv, E, nb, n);

        // ---- layers (proven r3 structure) ----
        k_gemm_scale<128><<<gBlk, 256, 0, stream>>>(x, W1, dinv, bufA, n);            // g1 (kills part)
        k_agg_gemm<<<aBlk, 256, 0, stream>>>(deg, ell, bufA, dinv, b1, W2, bufB, n);  // g2
        k_agg_gemm<<<aBlk, 256, 0, stream>>>(deg, ell, bufB, dinv, b2, W3, bufA, n);  // g3
        k_aggregate_ell<<<aBlk, 256, 0, stream>>>(deg, ell, bufA, bufB, dinv, b3, n); // h3

        k_score<<<scBlk, 256, 0, stream>>>(eli, eli + EL, bufB, out, EL);
    } else {
        // -------- fallback: proven r3 single-pass ELL path --------
        size_t o2 = 0;
        int*   cur   = (int*)(ws + o2);   o2 += alignup((size_t)n * 4);
        float* dinv2 = (float*)(ws + o2); o2 += alignup((size_t)n * 4);
        int*   ell2  = (int*)(ws + o2);   o2 += alignup((size_t)n * ELLW * 4);
        float* fA    = (float*)(ws + o2); o2 += alignup(nh * 4);
        float* fB    = (float*)(ws + o2); o2 += alignup(nh * 4);

        k_zero_int<<<nBlk, 256, 0, stream>>>(cur, n);
        k_ell_fill<<<eBlk, 256, 0, stream>>>(esrc, edst, cur, ell2, E);
        k_dinv_from_deg<<<nBlk, 256, 0, stream>>>(cur, dinv2, n);

        k_gemm_scale<128><<<gBlk, 256, 0, stream>>>(x, W1, dinv2, fA, n);
        k_agg_gemm<<<aBlk, 256, 0, stream>>>(cur, ell2, fA, dinv2, b1, W2, fB, n);
        k_agg_gemm<<<aBlk, 256, 0, stream>>>(cur, ell2, fB, dinv2, b2, W3, fA, n);
        k_aggregate_ell<<<aBlk, 256, 0, stream>>>(cur, ell2, fA, fB, dinv2, b3, n);

        k_score<<<scBlk, 256, 0, stream>>>(eli, eli + EL, fB, out, EL);
    }
}

// Round 7
// 585.941 us; speedup vs baseline: 7.2953x; 1.1147x over previous
//
#include <hip/hip_runtime.h>
#include <math.h>

#define HID 64
#define BSH 8                      // 256 nodes per bucket
#define BN 256
#define SRCBITS 17
#define SRCMASK ((1 << SRCBITS) - 1)
#define PB 512                     // partition chunks (one block each)
#define MAXNB 512                  // max buckets (n <= 131072)
#define ELLW 96

// ================= small utility =================
__global__ void k_zero_int(int* __restrict__ p, int n) {
    int i = blockIdx.x * blockDim.x + threadIdx.x;
    if (i < n) p[i] = 0;
}

// zero the padding row (index n) of both g buffers
__global__ void k_zero_padrow(float* __restrict__ a, float* __restrict__ b, long off) {
    int t = threadIdx.x;
    if (t < HID) { a[off + t] = 0.0f; b[off + t] = 0.0f; }
}

// ================= P1: per-chunk bucket histogram -> table[bu*PB + chunk] =================
__global__ void k_hist(const int* __restrict__ dst, int* __restrict__ table,
                       int E, int nb, int chunk) {
    __shared__ int lh[MAXNB];
    for (int t = threadIdx.x; t < nb; t += 256) lh[t] = 0;
    __syncthreads();
    int beg = blockIdx.x * chunk;
    int end = beg + chunk; if (end > E) end = E;
    for (int e = beg + threadIdx.x; e < end; e += 256)
        atomicAdd(&lh[dst[e] >> BSH], 1);
    __syncthreads();
    for (int t = threadIdx.x; t < nb; t += 256)
        table[t * PB + blockIdx.x] = lh[t];
}

// ================= P2a: per-bucket exclusive scan across chunks (in-place), rowsum out =================
__global__ void k_scanA(int* __restrict__ table, int* __restrict__ rowsum) {
    __shared__ int lds[PB];
    const int bu = blockIdx.x;
    const int t = threadIdx.x;
    int v = table[bu * PB + t];
    lds[t] = v;
    __syncthreads();
    for (int off = 1; off < PB; off <<= 1) {
        int u = (t >= off) ? lds[t - off] : 0;
        __syncthreads();
        lds[t] += u;
        __syncthreads();
    }
    table[bu * PB + t] = lds[t] - v;
    if (t == PB - 1) rowsum[bu] = lds[t];
}

// ================= P2b: exclusive scan of bucket totals (single block) =================
__global__ void k_scanB(int* __restrict__ rowsum, int nb) {
    __shared__ int lds[PB];
    const int t = threadIdx.x;
    int v = (t < nb) ? rowsum[t] : 0;
    lds[t] = v;
    __syncthreads();
    for (int off = 1; off < PB; off <<= 1) {
        int u = (t >= off) ? lds[t - off] : 0;
        __syncthreads();
        lds[t] += u;
        __syncthreads();
    }
    if (t < nb) rowsum[t] = lds[t] - v;
}

// ================= P2c: add bucket base to each row entry =================
__global__ void k_scanC(int* __restrict__ table, const int* __restrict__ rowsum, int L) {
    int i = blockIdx.x * 256 + threadIdx.x;
    if (i < L) table[i] += rowsum[i >> 9];  // i / PB, PB=512
}

// ================= P3: partition scatter, chunk-exclusive cursors =================
__global__ void k_pscatter(const int* __restrict__ src, const int* __restrict__ dst,
                           const int* __restrict__ excl, int* __restrict__ part,
                           int E, int nb, int chunk) {
    __shared__ int cur[MAXNB];
    for (int t = threadIdx.x; t < nb; t += 256) cur[t] = excl[t * PB + blockIdx.x];
    __syncthreads();
    int beg = blockIdx.x * chunk;
    int end = beg + chunk; if (end > E) end = E;
    for (int e = beg + threadIdx.x; e < end; e += 256) {
        int d = dst[e];
        int bu = d >> BSH;
        int pos = atomicAdd(&cur[bu], 1);
        part[pos] = ((d & (BN - 1)) << SRCBITS) | src[e];
    }
}

// ================= P4: per-bucket ELL fill + degree + dinv + pad-to-4 =================
__global__ void k_bell(const int* __restrict__ part, const int* __restrict__ excl,
                       int* __restrict__ ell, int* __restrict__ deg,
                       float* __restrict__ dinv, int E, int nb, int n) {
    __shared__ int cnt[BN];
    int b = blockIdx.x;
    for (int t = threadIdx.x; t < BN; t += 256) cnt[t] = 0;
    __syncthreads();
    int beg = excl[b * PB];
    int end = (b == nb - 1) ? E : excl[(b + 1) * PB];
    for (int i = beg + threadIdx.x; i < end; i += 256) {
        int c = part[i];
        int dl = c >> SRCBITS;
        int p = atomicAdd(&cnt[dl], 1);
        if (p < ELLW) ell[(size_t)((b << BSH) + dl) * ELLW + p] = c & SRCMASK;
    }
    __syncthreads();
    for (int t = threadIdx.x; t < BN; t += 256) {
        int node = (b << BSH) + t;
        if (node < n) {
            int dgv = cnt[t];
            int len = dgv < ELLW ? dgv : ELLW;
            int len4 = (len + 3) & ~3;      // ELLW%4==0 so len4<=ELLW
            int* r = ell + (size_t)node * ELLW;
            for (int p = len; p < len4; ++p) r[p] = n;   // pad -> zero row
            deg[node] = dgv;
            dinv[node] = rsqrtf((float)(dgv + 1));
        }
    }
}

// ================= GEMM + dinv scale: g[i][c] = dinv[i] * (x @ W)[i][c] =================
template<int K>
__launch_bounds__(256)
__global__ void k_gemm_scale(const float* __restrict__ x, const float* __restrict__ W,
                             const float* __restrict__ dinv, float* __restrict__ g, int n) {
    __shared__ float sW[K * HID];
    for (int t = threadIdx.x; t < K * HID; t += 256) sW[t] = W[t];
    __syncthreads();
    const int lane = threadIdx.x & 63;
    const int rowInBlk = threadIdx.x >> 6;
    const int ROWS = 32;
    const int base = blockIdx.x * ROWS;
    for (int r = rowInBlk; r < ROWS; r += 4) {
        int i = base + r;
        if (i >= n) return;
        const float* xr = x + (size_t)i * K;
        float acc = 0.0f;
#pragma unroll
        for (int k = 0; k < K; k += 4) {
            float4 xv = *(const float4*)(xr + k);
            acc = fmaf(xv.x, sW[(k + 0) * HID + lane], acc);
            acc = fmaf(xv.y, sW[(k + 1) * HID + lane], acc);
            acc = fmaf(xv.z, sW[(k + 2) * HID + lane], acc);
            acc = fmaf(xv.w, sW[(k + 3) * HID + lane], acc);
        }
        g[(size_t)i * HID + lane] = acc * dinv[i];
    }
}

// ================= agg v2: 16-lane float4 groups, 4 edges per wave-load =================
// group grp (lane>>4) handles edges j == grp (mod 4); lane's float4 = channels (lane&15)*4..+3
// cross-group shfl-xor reduce; fused epilogue; FUSE adds relu + next 64x64 GEMM.
template<bool FUSE>
__launch_bounds__(256)
__global__ void k_agg4(const int* __restrict__ deg, const int* __restrict__ ell,
                       const float* __restrict__ g, const float* __restrict__ dinv,
                       const float* __restrict__ bias, const float* __restrict__ Wn,
                       float* __restrict__ outp, int n) {
    __shared__ float sW[FUSE ? HID * HID : 4];
    __shared__ float sH[4][HID];
    if (FUSE) {
        for (int t = threadIdx.x; t < HID * HID; t += 256) sW[t] = Wn[t];
    }
    const int wv = threadIdx.x >> 6;
    const int lane = threadIdx.x & 63;
    const int grp = lane >> 4;
    const int cq = lane & 15;
    const int node = blockIdx.x * 4 + wv;
    float4 acc = make_float4(0.0f, 0.0f, 0.0f, 0.0f);
    float di = 0.0f;
    if (node < n) {
        di = dinv[node];
        int dg = deg[node];
        int len = dg < ELLW ? dg : ELLW;
        int len4 = (len + 3) & ~3;
        const int* row = ell + (size_t)node * ELLW;
        int j = grp;
        for (; j + 4 < len4; j += 8) {        // pair {j, j+4}: 8 wave-edges in flight
            int s0 = row[j];
            int s1 = row[j + 4];
            const float4 v0 = *(const float4*)(g + (size_t)s0 * HID + cq * 4);
            const float4 v1 = *(const float4*)(g + (size_t)s1 * HID + cq * 4);
            acc.x += v0.x + v1.x;
            acc.y += v0.y + v1.y;
            acc.z += v0.z + v1.z;
            acc.w += v0.w + v1.w;
        }
        for (; j < len4; j += 4) {
            int s0 = row[j];
            const float4 v0 = *(const float4*)(g + (size_t)s0 * HID + cq * 4);
            acc.x += v0.x; acc.y += v0.y; acc.z += v0.z; acc.w += v0.w;
        }
    }
    // cross-group reduce: sum lanes {cq, cq+16, cq+32, cq+48}
    acc.x += __shfl_xor(acc.x, 16); acc.y += __shfl_xor(acc.y, 16);
    acc.z += __shfl_xor(acc.z, 16); acc.w += __shfl_xor(acc.w, 16);
    acc.x += __shfl_xor(acc.x, 32); acc.y += __shfl_xor(acc.y, 32);
    acc.z += __shfl_xor(acc.z, 32); acc.w += __shfl_xor(acc.w, 32);
    if (node < n) {
        const float4 self = *(const float4*)(g + (size_t)node * HID + cq * 4);
        const float4 bv = *(const float4*)(bias + cq * 4);
        float4 h;
        h.x = di * (acc.x + self.x) + bv.x;
        h.y = di * (acc.y + self.y) + bv.y;
        h.z = di * (acc.z + self.z) + bv.z;
        h.w = di * (acc.w + self.w) + bv.w;
        if (!FUSE) {
            if (grp == 0) *(float4*)(outp + (size_t)node * HID + cq * 4) = h;
        } else {
            h.x = fmaxf(h.x, 0.0f); h.y = fmaxf(h.y, 0.0f);
            h.z = fmaxf(h.z, 0.0f); h.w = fmaxf(h.w, 0.0f);
            if (grp == 0) *(float4*)(&sH[wv][cq * 4]) = h;
        }
    }
    if (FUSE) {
        __syncthreads();
        if (node < n) {
            const float* hr = sH[wv];
            float o = 0.0f;
#pragma unroll
            for (int k = 0; k < HID; k += 4) {
                o = fmaf(hr[k + 0], sW[(k + 0) * HID + lane], o);
                o = fmaf(hr[k + 1], sW[(k + 1) * HID + lane], o);
                o = fmaf(hr[k + 2], sW[(k + 2) * HID + lane], o);
                o = fmaf(hr[k + 3], sW[(k + 3) * HID + lane], o);
            }
            outp[(size_t)node * HID + lane] = o * di;
        }
    }
}

// ================= link scores =================
__launch_bounds__(256)
__global__ void k_score(const int* __restrict__ ls, const int* __restrict__ ld,
                        const float* __restrict__ h, float* __restrict__ out, int EL) {
    long t = (long)blockIdx.x * 256 + threadIdx.x;
    long e = t >> 4;
    if (e >= EL) return;
    int q = (int)(t & 15);
    int s = ls[e];
    int d = ld[e];
    float4 a  = *(const float4*)(h + (size_t)s * HID + q * 4);
    float4 bb = *(const float4*)(h + (size_t)d * HID + q * 4);
    float p = a.x * bb.x + a.y * bb.y + a.z * bb.z + a.w * bb.w;
    p += __shfl_xor(p, 1);
    p += __shfl_xor(p, 2);
    p += __shfl_xor(p, 4);
    p += __shfl_xor(p, 8);
    if (q == 0) out[e] = 1.0f / (1.0f + __expf(-p));
}

// ================= fallback: proven r3 kernels =================
__global__ void k_ell_fill(const int* __restrict__ src, const int* __restrict__ dst,
                           int* __restrict__ cur, int* __restrict__ ell, int E) {
    int e = blockIdx.x * blockDim.x + threadIdx.x;
    if (e < E) {
        int d = dst[e];
        int p = atomicAdd(&cur[d], 1);
        if (p < ELLW) ell[(size_t)d * ELLW + p] = src[e];
    }
}
__global__ void k_dinv_from_deg(const int* __restrict__ deg, float* __restrict__ dinv, int n) {
    int i = blockIdx.x * blockDim.x + threadIdx.x;
    if (i < n) dinv[i] = rsqrtf((float)(deg[i] + 1));
}
__launch_bounds__(256)
__global__ void k_agg_gemm(const int* __restrict__ deg, const int* __restrict__ ell,
                           const float* __restrict__ g, const float* __restrict__ dinv,
                           const float* __restrict__ bias, const float* __restrict__ Wn,
                           float* __restrict__ gout, int n) {
    __shared__ float sW[HID * HID];
    __shared__ float sH[4][HID];
    for (int t = threadIdx.x; t < HID * HID; t += 256) sW[t] = Wn[t];
    const int wv = threadIdx.x >> 6;
    const int lane = threadIdx.x & 63;
    const int node = blockIdx.x * 4 + wv;
    if (node < n) {
        int dg = deg[node];
        int len = dg < ELLW ? dg : ELLW;
        const int* row = ell + (size_t)node * ELLW;
        float acc = g[(size_t)node * HID + lane];
        int j = 0;
        for (; j + 4 <= len; j += 4) {
            int s0 = row[j], s1 = row[j + 1], s2 = row[j + 2], s3 = row[j + 3];
            acc += (g[(size_t)s0 * HID + lane] + g[(size_t)s1 * HID + lane]) +
                   (g[(size_t)s2 * HID + lane] + g[(size_t)s3 * HID + lane]);
        }
        for (; j < len; ++j) acc += g[(size_t)row[j] * HID + lane];
        float h = fmaxf(dinv[node] * acc + bias[lane], 0.0f);
        sH[wv][lane] = h;
    }
    __syncthreads();
    if (node < n) {
        const float* hr = sH[wv];
        float o = 0.0f;
#pragma unroll
        for (int k = 0; k < HID; k += 4) {
            o = fmaf(hr[k + 0], sW[(k + 0) * HID + lane], o);
            o = fmaf(hr[k + 1], sW[(k + 1) * HID + lane], o);
            o = fmaf(hr[k + 2], sW[(k + 2) * HID + lane], o);
            o = fmaf(hr[k + 3], sW[(k + 3) * HID + lane], o);
        }
        gout[(size_t)node * HID + lane] = o * dinv[node];
    }
}
__launch_bounds__(256)
__global__ void k_aggregate_ell(const int* __restrict__ deg, const int* __restrict__ ell,
                                const float* __restrict__ g, float* __restrict__ out,
                                const float* __restrict__ dinv, const float* __restrict__ b,
                                int n) {
    int node = (int)(((long)blockIdx.x * 256 + threadIdx.x) >> 6);
    int lane = threadIdx.x & 63;
    if (node >= n) return;
    int dg = deg[node];
    int len = dg < ELLW ? dg : ELLW;
    const int* row = ell + (size_t)node * ELLW;
    float acc = g[(size_t)node * HID + lane];
    int j = 0;
    for (; j + 4 <= len; j += 4) {
        int s0 = row[j], s1 = row[j + 1], s2 = row[j + 2], s3 = row[j + 3];
        acc += (g[(size_t)s0 * HID + lane] + g[(size_t)s1 * HID + lane]) +
               (g[(size_t)s2 * HID + lane] + g[(size_t)s3 * HID + lane]);
    }
    for (; j < len; ++j) acc += g[(size_t)row[j] * HID + lane];
    out[(size_t)node * HID + lane] = dinv[node] * acc + b[lane];
}

static inline size_t alignup(size_t v) { return (v + 255) & ~(size_t)255; }

extern "C" void kernel_launch(void* const* d_in, const int* in_sizes, int n_in,
                              void* d_out, int out_size, void* d_ws, size_t ws_size,
                              hipStream_t stream) {
    const float* x  = (const float*)d_in[0];
    const float* W1 = (const float*)d_in[1];
    const float* b1 = (const float*)d_in[2];
    const float* W2 = (const float*)d_in[3];
    const float* b2 = (const float*)d_in[4];
    const float* W3 = (const float*)d_in[5];
    const float* b3 = (const float*)d_in[6];
    const int* ei  = (const int*)d_in[7];
    const int* eli = (const int*)d_in[8];

    const int n  = in_sizes[0] / 128;
    const int E  = in_sizes[7] / 2;
    const int EL = in_sizes[8] / 2;
    float* out = (float*)d_out;

    const int* esrc = ei;
    const int* edst = ei + E;

    const long nh = (long)n * HID;
    const int nBlk  = (n + 255) / 256;
    const int eBlk  = (E + 255) / 256;
    const int gBlk  = (n + 31) / 32;
    const int aBlk  = (n + 3) / 4;
    const int scBlk = (int)(((long)EL * 16 + 255) / 256);
    const int nb = (n + BN - 1) >> BSH;
    const int chunk = (E + PB - 1) / PB;

    // -------- workspace layout (partitioned-build path) --------
    size_t o = 0;
    char* ws = (char*)d_ws;
    int*   table  = (int*)(ws + o); o += alignup((size_t)MAXNB * PB * 4);
    int*   rowsum = (int*)(ws + o); o += alignup((size_t)MAXNB * 4);
    int*   deg    = (int*)(ws + o); o += alignup((size_t)n * 4);
    float* dinv   = (float*)(ws + o); o += alignup((size_t)n * 4);
    int*   ell    = (int*)(ws + o); o += alignup((size_t)n * ELLW * 4);
    float* bufA   = (float*)(ws + o); o += alignup((nh + HID) * 4);   // +1 zero pad row
    float* bufB   = (float*)(ws + o); o += alignup((nh + HID) * 4);
    const size_t need_part = o;
    int* part = (int*)bufA;  // part (E ints) dead before gemm writes bufA; ends below pad row

    if (n <= (1 << SRCBITS) && nb <= MAXNB && (long)E * 4 <= nh * 4 && ws_size >= need_part) {
        // ---- build: contention-free two-pass partition + per-bucket ELL ----
        k_hist<<<PB, 256, 0, stream>>>(edst, table, E, nb, chunk);
        k_scanA<<<nb, PB, 0, stream>>>(table, rowsum);
        k_scanB<<<1, PB, 0, stream>>>(rowsum, nb);
        k_scanC<<<(nb * PB + 255) / 256, 256, 0, stream>>>(table, rowsum, nb * PB);
        k_pscatter<<<PB, 256, 0, stream>>>(esrc, edst, table, part, E, nb, chunk);
        k_bell<<<nb, 256, 0, stream>>>(part, table, ell, deg, dinv, E, nb, n);
        k_zero_padrow<<<1, 64, 0, stream>>>(bufA, bufB, nh);

        // ---- layers ----
        k_gemm_scale<128><<<gBlk, 256, 0, stream>>>(x, W1, dinv, bufA, n);           // g1 (kills part)
        k_agg4<true ><<<aBlk, 256, 0, stream>>>(deg, ell, bufA, dinv, b1, W2, bufB, n); // g2
        k_agg4<true ><<<aBlk, 256, 0, stream>>>(deg, ell, bufB, dinv, b2, W3, bufA, n); // g3
        k_agg4<false><<<aBlk, 256, 0, stream>>>(deg, ell, bufA, dinv, b3, (const float*)0, bufB, n); // h3

        k_score<<<scBlk, 256, 0, stream>>>(eli, eli + EL, bufB, out, EL);
    } else {
        // -------- fallback: proven r3 single-pass ELL path --------
        size_t o2 = 0;
        int*   cur   = (int*)(ws + o2);   o2 += alignup((size_t)n * 4);
        float* dinv2 = (float*)(ws + o2); o2 += alignup((size_t)n * 4);
        int*   ell2  = (int*)(ws + o2);   o2 += alignup((size_t)n * ELLW * 4);
        float* fA    = (float*)(ws + o2); o2 += alignup(nh * 4);
        float* fB    = (float*)(ws + o2); o2 += alignup(nh * 4);

        k_zero_int<<<nBlk, 256, 0, stream>>>(cur, n);
        k_ell_fill<<<eBlk, 256, 0, stream>>>(esrc, edst, cur, ell2, E);
        k_dinv_from_deg<<<nBlk, 256, 0, stream>>>(cur, dinv2, n);

        k_gemm_scale<128><<<gBlk, 256, 0, stream>>>(x, W1, dinv2, fA, n);
        k_agg_gemm<<<aBlk, 256, 0, stream>>>(cur, ell2, fA, dinv2, b1, W2, fB, n);
        k_agg_gemm<<<aBlk, 256, 0, stream>>>(cur, ell2, fB, dinv2, b2, W3, fA, n);
        k_aggregate_ell<<<aBlk, 256, 0, stream>>>(cur, ell2, fA, fB, dinv2, b3, n);

        k_score<<<scBlk, 256, 0, stream>>>(eli, eli + EL, fB, out, EL);
    }
}

// Round 8
// 449.146 us; speedup vs baseline: 9.5172x; 1.3046x over previous
//
#include <hip/hip_runtime.h>
#include <math.h>

#define HID 64
#define BSH 8                      // 256 nodes per bucket
#define BN 256
#define SRCBITS 17
#define SRCMASK ((1 << SRCBITS) - 1)
#define PB 512                     // partition chunks
#define MAXNB 512                  // max buckets (n <= 131072)
#define ELLW 96

typedef unsigned short bfraw;      // raw bf16 storage

__device__ __forceinline__ float bf_lo(unsigned u) { return __uint_as_float(u << 16); }
__device__ __forceinline__ float bf_hi(unsigned u) { return __uint_as_float(u & 0xffff0000u); }
__device__ __forceinline__ unsigned short f2bf(float f) {
    unsigned u = __float_as_uint(f);
    u += 0x7fffu + ((u >> 16) & 1u);   // round-to-nearest-even (finite values)
    return (unsigned short)(u >> 16);
}
__device__ __forceinline__ unsigned pack2(float a, float b) {
    return (unsigned)f2bf(a) | ((unsigned)f2bf(b) << 16);
}

// ================= small utility =================
__global__ void k_zero_int(int* __restrict__ p, int n) {
    int i = blockIdx.x * blockDim.x + threadIdx.x;
    if (i < n) p[i] = 0;
}

// zero the padding row (index n) of both bf16 buffers
__global__ void k_zero_padrow(bfraw* __restrict__ a, bfraw* __restrict__ b, long off) {
    int t = threadIdx.x;
    if (t < HID) { a[off + t] = 0; b[off + t] = 0; }
}

// ================= P1: per-chunk bucket histogram =================
__global__ void k_hist(const int* __restrict__ dst, int* __restrict__ table,
                       int E, int nb, int chunk) {
    __shared__ int lh[MAXNB];
    for (int t = threadIdx.x; t < nb; t += 256) lh[t] = 0;
    __syncthreads();
    int beg = blockIdx.x * chunk;
    int end = beg + chunk; if (end > E) end = E;
    for (int e = beg + threadIdx.x; e < end; e += 256)
        atomicAdd(&lh[dst[e] >> BSH], 1);
    __syncthreads();
    for (int t = threadIdx.x; t < nb; t += 256)
        table[t * PB + blockIdx.x] = lh[t];
}

// ================= P2a: per-bucket exclusive scan across chunks =================
__global__ void k_scanA(int* __restrict__ table, int* __restrict__ rowsum) {
    __shared__ int lds[PB];
    const int bu = blockIdx.x;
    const int t = threadIdx.x;
    int v = table[bu * PB + t];
    lds[t] = v;
    __syncthreads();
    for (int off = 1; off < PB; off <<= 1) {
        int u = (t >= off) ? lds[t - off] : 0;
        __syncthreads();
        lds[t] += u;
        __syncthreads();
    }
    table[bu * PB + t] = lds[t] - v;
    if (t == PB - 1) rowsum[bu] = lds[t];
}

// ================= P2b: exclusive scan of bucket totals =================
__global__ void k_scanB(int* __restrict__ rowsum, int nb) {
    __shared__ int lds[PB];
    const int t = threadIdx.x;
    int v = (t < nb) ? rowsum[t] : 0;
    lds[t] = v;
    __syncthreads();
    for (int off = 1; off < PB; off <<= 1) {
        int u = (t >= off) ? lds[t - off] : 0;
        __syncthreads();
        lds[t] += u;
        __syncthreads();
    }
    if (t < nb) rowsum[t] = lds[t] - v;
}

// ================= P2c: add bucket base =================
__global__ void k_scanC(int* __restrict__ table, const int* __restrict__ rowsum, int L) {
    int i = blockIdx.x * 256 + threadIdx.x;
    if (i < L) table[i] += rowsum[i >> 9];  // i / PB, PB=512
}

// ================= P3: partition scatter =================
__global__ void k_pscatter(const int* __restrict__ src, const int* __restrict__ dst,
                           const int* __restrict__ excl, int* __restrict__ part,
                           int E, int nb, int chunk) {
    __shared__ int cur[MAXNB];
    for (int t = threadIdx.x; t < nb; t += 256) cur[t] = excl[t * PB + blockIdx.x];
    __syncthreads();
    int beg = blockIdx.x * chunk;
    int end = beg + chunk; if (end > E) end = E;
    for (int e = beg + threadIdx.x; e < end; e += 256) {
        int d = dst[e];
        int bu = d >> BSH;
        int pos = atomicAdd(&cur[bu], 1);
        part[pos] = ((d & (BN - 1)) << SRCBITS) | src[e];
    }
}

// ================= P4: per-bucket ELL fill + degree + dinv + pad-to-8 =================
__global__ void k_bell(const int* __restrict__ part, const int* __restrict__ excl,
                       int* __restrict__ ell, int* __restrict__ deg,
                       float* __restrict__ dinv, int E, int nb, int n) {
    __shared__ int cnt[BN];
    int b = blockIdx.x;
    for (int t = threadIdx.x; t < BN; t += 256) cnt[t] = 0;
    __syncthreads();
    int beg = excl[b * PB];
    int end = (b == nb - 1) ? E : excl[(b + 1) * PB];
    for (int i = beg + threadIdx.x; i < end; i += 256) {
        int c = part[i];
        int dl = c >> SRCBITS;
        int p = atomicAdd(&cnt[dl], 1);
        if (p < ELLW) ell[(size_t)((b << BSH) + dl) * ELLW + p] = c & SRCMASK;
    }
    __syncthreads();
    for (int t = threadIdx.x; t < BN; t += 256) {
        int node = (b << BSH) + t;
        if (node < n) {
            int dgv = cnt[t];
            int len = dgv < ELLW ? dgv : ELLW;
            int len8 = (len + 7) & ~7;      // ELLW%8==0 so len8<=ELLW
            int* r = ell + (size_t)node * ELLW;
            for (int p = len; p < len8; ++p) r[p] = n;   // pad -> zero row
            deg[node] = dgv;
            dinv[node] = rsqrtf((float)(dgv + 1));
        }
    }
}

// ================= GEMM + dinv scale -> bf16: g[i][c] = bf16(dinv[i]*(x@W)[i][c]) =================
template<int K>
__launch_bounds__(256)
__global__ void k_gemm_bf(const float* __restrict__ x, const float* __restrict__ W,
                          const float* __restrict__ dinv, bfraw* __restrict__ g, int n) {
    __shared__ float sW[K * HID];
    for (int t = threadIdx.x; t < K * HID; t += 256) sW[t] = W[t];
    __syncthreads();
    const int lane = threadIdx.x & 63;
    const int rowInBlk = threadIdx.x >> 6;
    const int ROWS = 32;
    const int base = blockIdx.x * ROWS;
    for (int r = rowInBlk; r < ROWS; r += 4) {
        int i = base + r;
        if (i >= n) return;
        const float* xr = x + (size_t)i * K;
        float acc = 0.0f;
#pragma unroll
        for (int k = 0; k < K; k += 4) {
            float4 xv = *(const float4*)(xr + k);
            acc = fmaf(xv.x, sW[(k + 0) * HID + lane], acc);
            acc = fmaf(xv.y, sW[(k + 1) * HID + lane], acc);
            acc = fmaf(xv.z, sW[(k + 2) * HID + lane], acc);
            acc = fmaf(xv.w, sW[(k + 3) * HID + lane], acc);
        }
        g[(size_t)i * HID + lane] = f2bf(acc * dinv[i]);
    }
}

// ================= bf16 aggregation: 8-lane uint4 groups, 8 edges per wave-load =================
// group grp=lane>>3 handles edge slots j==grp (mod 8); lane covers channels (lane&7)*8..+7.
// FUSE: h=relu(dinv*(sum+self)+b); out = bf16(dinv * (W^T h)).  !FUSE: out = bf16(h), no relu.
template<bool FUSE>
__launch_bounds__(256)
__global__ void k_aggb(const int* __restrict__ deg, const int* __restrict__ ell,
                       const bfraw* __restrict__ g, const float* __restrict__ dinv,
                       const float* __restrict__ bias, const float* __restrict__ Wn,
                       bfraw* __restrict__ outp, int n) {
    __shared__ float sW[FUSE ? HID * HID : 4];
    __shared__ float sH[4][HID];
    if (FUSE) {
        for (int t = threadIdx.x; t < HID * HID; t += 256) sW[t] = Wn[t];
    }
    const int wv = threadIdx.x >> 6;
    const int lane = threadIdx.x & 63;
    const int grp = lane >> 3;
    const int cq = lane & 7;
    const int node = blockIdx.x * 4 + wv;
    float a0 = 0, a1 = 0, a2 = 0, a3 = 0, a4 = 0, a5 = 0, a6 = 0, a7 = 0;
    if (node < n) {
        int dg = deg[node];
        int len = dg < ELLW ? dg : ELLW;
        int len8 = (len + 7) & ~7;
        const int* row = ell + (size_t)node * ELLW;
        int j = grp;
        for (; j + 8 < len8; j += 16) {      // pair {j, j+8}: 16 wave-edges in flight
            int s0 = row[j];
            int s1 = row[j + 8];
            const uint4 v0 = *(const uint4*)(g + (size_t)s0 * HID + cq * 8);
            const uint4 v1 = *(const uint4*)(g + (size_t)s1 * HID + cq * 8);
            a0 += bf_lo(v0.x) + bf_lo(v1.x);
            a1 += bf_hi(v0.x) + bf_hi(v1.x);
            a2 += bf_lo(v0.y) + bf_lo(v1.y);
            a3 += bf_hi(v0.y) + bf_hi(v1.y);
            a4 += bf_lo(v0.z) + bf_lo(v1.z);
            a5 += bf_hi(v0.z) + bf_hi(v1.z);
            a6 += bf_lo(v0.w) + bf_lo(v1.w);
            a7 += bf_hi(v0.w) + bf_hi(v1.w);
        }
        for (; j < len8; j += 8) {
            int s0 = row[j];
            const uint4 v0 = *(const uint4*)(g + (size_t)s0 * HID + cq * 8);
            a0 += bf_lo(v0.x); a1 += bf_hi(v0.x);
            a2 += bf_lo(v0.y); a3 += bf_hi(v0.y);
            a4 += bf_lo(v0.z); a5 += bf_hi(v0.z);
            a6 += bf_lo(v0.w); a7 += bf_hi(v0.w);
        }
    }
    // reduce across 8 groups (group bits are lane bits 3..5)
    a0 += __shfl_xor(a0, 8);  a1 += __shfl_xor(a1, 8);  a2 += __shfl_xor(a2, 8);  a3 += __shfl_xor(a3, 8);
    a4 += __shfl_xor(a4, 8);  a5 += __shfl_xor(a5, 8);  a6 += __shfl_xor(a6, 8);  a7 += __shfl_xor(a7, 8);
    a0 += __shfl_xor(a0, 16); a1 += __shfl_xor(a1, 16); a2 += __shfl_xor(a2, 16); a3 += __shfl_xor(a3, 16);
    a4 += __shfl_xor(a4, 16); a5 += __shfl_xor(a5, 16); a6 += __shfl_xor(a6, 16); a7 += __shfl_xor(a7, 16);
    a0 += __shfl_xor(a0, 32); a1 += __shfl_xor(a1, 32); a2 += __shfl_xor(a2, 32); a3 += __shfl_xor(a3, 32);
    a4 += __shfl_xor(a4, 32); a5 += __shfl_xor(a5, 32); a6 += __shfl_xor(a6, 32); a7 += __shfl_xor(a7, 32);
    if (node < n && grp == 0) {
        const uint4 sv = *(const uint4*)(g + (size_t)node * HID + cq * 8);
        float di = dinv[node];
        const float4 bv0 = *(const float4*)(bias + cq * 8);
        const float4 bv1 = *(const float4*)(bias + cq * 8 + 4);
        float h0 = di * (a0 + bf_lo(sv.x)) + bv0.x;
        float h1 = di * (a1 + bf_hi(sv.x)) + bv0.y;
        float h2 = di * (a2 + bf_lo(sv.y)) + bv0.z;
        float h3 = di * (a3 + bf_hi(sv.y)) + bv0.w;
        float h4 = di * (a4 + bf_lo(sv.z)) + bv1.x;
        float h5 = di * (a5 + bf_hi(sv.z)) + bv1.y;
        float h6 = di * (a6 + bf_lo(sv.w)) + bv1.z;
        float h7 = di * (a7 + bf_hi(sv.w)) + bv1.w;
        if (!FUSE) {
            uint4 o;
            o.x = pack2(h0, h1); o.y = pack2(h2, h3);
            o.z = pack2(h4, h5); o.w = pack2(h6, h7);
            *(uint4*)(outp + (size_t)node * HID + cq * 8) = o;
        } else {
            h0 = fmaxf(h0, 0.0f); h1 = fmaxf(h1, 0.0f); h2 = fmaxf(h2, 0.0f); h3 = fmaxf(h3, 0.0f);
            h4 = fmaxf(h4, 0.0f); h5 = fmaxf(h5, 0.0f); h6 = fmaxf(h6, 0.0f); h7 = fmaxf(h7, 0.0f);
            *(float4*)(&sH[wv][cq * 8])     = make_float4(h0, h1, h2, h3);
            *(float4*)(&sH[wv][cq * 8 + 4]) = make_float4(h4, h5, h6, h7);
        }
    }
    if (FUSE) {
        __syncthreads();
        if (node < n) {
            const float* hr = sH[wv];
            float o = 0.0f;
#pragma unroll
            for (int k = 0; k < HID; k += 4) {
                o = fmaf(hr[k + 0], sW[(k + 0) * HID + lane], o);
                o = fmaf(hr[k + 1], sW[(k + 1) * HID + lane], o);
                o = fmaf(hr[k + 2], sW[(k + 2) * HID + lane], o);
                o = fmaf(hr[k + 3], sW[(k + 3) * HID + lane], o);
            }
            outp[(size_t)node * HID + lane] = f2bf(o * dinv[node]);
        }
    }
}

// ================= link scores from bf16 h3: 8 lanes/edge =================
__launch_bounds__(256)
__global__ void k_score_bf(const int* __restrict__ ls, const int* __restrict__ ld,
                           const bfraw* __restrict__ h, float* __restrict__ out, int EL) {
    const int wv = threadIdx.x >> 6;
    const int lane = threadIdx.x & 63;
    const int grp = lane >> 3;
    const int cq = lane & 7;
    long e = (long)blockIdx.x * 32 + wv * 8 + grp;
    if (e >= EL) return;   // group-uniform
    int s = ls[e];
    int d = ld[e];
    const uint4 va = *(const uint4*)(h + (size_t)s * HID + cq * 8);
    const uint4 vb = *(const uint4*)(h + (size_t)d * HID + cq * 8);
    float p = bf_lo(va.x) * bf_lo(vb.x) + bf_hi(va.x) * bf_hi(vb.x)
            + bf_lo(va.y) * bf_lo(vb.y) + bf_hi(va.y) * bf_hi(vb.y)
            + bf_lo(va.z) * bf_lo(vb.z) + bf_hi(va.z) * bf_hi(vb.z)
            + bf_lo(va.w) * bf_lo(vb.w) + bf_hi(va.w) * bf_hi(vb.w);
    p += __shfl_xor(p, 1);
    p += __shfl_xor(p, 2);
    p += __shfl_xor(p, 4);
    if (cq == 0) out[e] = 1.0f / (1.0f + __expf(-p));
}

// ================= fallback: proven r3 fp32 kernels =================
__global__ void k_ell_fill(const int* __restrict__ src, const int* __restrict__ dst,
                           int* __restrict__ cur, int* __restrict__ ell, int E) {
    int e = blockIdx.x * blockDim.x + threadIdx.x;
    if (e < E) {
        int d = dst[e];
        int p = atomicAdd(&cur[d], 1);
        if (p < ELLW) ell[(size_t)d * ELLW + p] = src[e];
    }
}
__global__ void k_dinv_from_deg(const int* __restrict__ deg, float* __restrict__ dinv, int n) {
    int i = blockIdx.x * blockDim.x + threadIdx.x;
    if (i < n) dinv[i] = rsqrtf((float)(deg[i] + 1));
}
template<int K>
__launch_bounds__(256)
__global__ void k_gemm_f32(const float* __restrict__ x, const float* __restrict__ W,
                           const float* __restrict__ dinv, float* __restrict__ g, int n) {
    __shared__ float sW[K * HID];
    for (int t = threadIdx.x; t < K * HID; t += 256) sW[t] = W[t];
    __syncthreads();
    const int lane = threadIdx.x & 63;
    const int rowInBlk = threadIdx.x >> 6;
    const int ROWS = 32;
    const int base = blockIdx.x * ROWS;
    for (int r = rowInBlk; r < ROWS; r += 4) {
        int i = base + r;
        if (i >= n) return;
        const float* xr = x + (size_t)i * K;
        float acc = 0.0f;
#pragma unroll
        for (int k = 0; k < K; k += 4) {
            float4 xv = *(const float4*)(xr + k);
            acc = fmaf(xv.x, sW[(k + 0) * HID + lane], acc);
            acc = fmaf(xv.y, sW[(k + 1) * HID + lane], acc);
            acc = fmaf(xv.z, sW[(k + 2) * HID + lane], acc);
            acc = fmaf(xv.w, sW[(k + 3) * HID + lane], acc);
        }
        g[(size_t)i * HID + lane] = acc * dinv[i];
    }
}
__launch_bounds__(256)
__global__ void k_agg_gemm(const int* __restrict__ deg, const int* __restrict__ ell,
                           const float* __restrict__ g, const float* __restrict__ dinv,
                           const float* __restrict__ bias, const float* __restrict__ Wn,
                           float* __restrict__ gout, int n) {
    __shared__ float sW[HID * HID];
    __shared__ float sH[4][HID];
    for (int t = threadIdx.x; t < HID * HID; t += 256) sW[t] = Wn[t];
    const int wv = threadIdx.x >> 6;
    const int lane = threadIdx.x & 63;
    const int node = blockIdx.x * 4 + wv;
    if (node < n) {
        int dg = deg[node];
        int len = dg < ELLW ? dg : ELLW;
        const int* row = ell + (size_t)node * ELLW;
        float acc = g[(size_t)node * HID + lane];
        int j = 0;
        for (; j + 4 <= len; j += 4) {
            int s0 = row[j], s1 = row[j + 1], s2 = row[j + 2], s3 = row[j + 3];
            acc += (g[(size_t)s0 * HID + lane] + g[(size_t)s1 * HID + lane]) +
                   (g[(size_t)s2 * HID + lane] + g[(size_t)s3 * HID + lane]);
        }
        for (; j < len; ++j) acc += g[(size_t)row[j] * HID + lane];
        float h = fmaxf(dinv[node] * acc + bias[lane], 0.0f);
        sH[wv][lane] = h;
    }
    __syncthreads();
    if (node < n) {
        const float* hr = sH[wv];
        float o = 0.0f;
#pragma unroll
        for (int k = 0; k < HID; k += 4) {
            o = fmaf(hr[k + 0], sW[(k + 0) * HID + lane], o);
            o = fmaf(hr[k + 1], sW[(k + 1) * HID + lane], o);
            o = fmaf(hr[k + 2], sW[(k + 2) * HID + lane], o);
            o = fmaf(hr[k + 3], sW[(k + 3) * HID + lane], o);
        }
        gout[(size_t)node * HID + lane] = o * dinv[node];
    }
}
__launch_bounds__(256)
__global__ void k_aggregate_ell(const int* __restrict__ deg, const int* __restrict__ ell,
                                const float* __restrict__ g, float* __restrict__ out,
                                const float* __restrict__ dinv, const float* __restrict__ b,
                                int n) {
    int node = (int)(((long)blockIdx.x * 256 + threadIdx.x) >> 6);
    int lane = threadIdx.x & 63;
    if (node >= n) return;
    int dg = deg[node];
    int len = dg < ELLW ? dg : ELLW;
    const int* row = ell + (size_t)node * ELLW;
    float acc = g[(size_t)node * HID + lane];
    int j = 0;
    for (; j + 4 <= len; j += 4) {
        int s0 = row[j], s1 = row[j + 1], s2 = row[j + 2], s3 = row[j + 3];
        acc += (g[(size_t)s0 * HID + lane] + g[(size_t)s1 * HID + lane]) +
               (g[(size_t)s2 * HID + lane] + g[(size_t)s3 * HID + lane]);
    }
    for (; j < len; ++j) acc += g[(size_t)row[j] * HID + lane];
    out[(size_t)node * HID + lane] = dinv[node] * acc + b[lane];
}
__launch_bounds__(256)
__global__ void k_score_f32(const int* __restrict__ ls, const int* __restrict__ ld,
                            const float* __restrict__ h, float* __restrict__ out, int EL) {
    long t = (long)blockIdx.x * 256 + threadIdx.x;
    long e = t >> 4;
    if (e >= EL) return;
    int q = (int)(t & 15);
    int s = ls[e];
    int d = ld[e];
    float4 a  = *(const float4*)(h + (size_t)s * HID + q * 4);
    float4 bb = *(const float4*)(h + (size_t)d * HID + q * 4);
    float p = a.x * bb.x + a.y * bb.y + a.z * bb.z + a.w * bb.w;
    p += __shfl_xor(p, 1);
    p += __shfl_xor(p, 2);
    p += __shfl_xor(p, 4);
    p += __shfl_xor(p, 8);
    if (q == 0) out[e] = 1.0f / (1.0f + __expf(-p));
}

static inline size_t alignup(size_t v) { return (v + 255) & ~(size_t)255; }

extern "C" void kernel_launch(void* const* d_in, const int* in_sizes, int n_in,
                              void* d_out, int out_size, void* d_ws, size_t ws_size,
                              hipStream_t stream) {
    const float* x  = (const float*)d_in[0];
    const float* W1 = (const float*)d_in[1];
    const float* b1 = (const float*)d_in[2];
    const float* W2 = (const float*)d_in[3];
    const float* b2 = (const float*)d_in[4];
    const float* W3 = (const float*)d_in[5];
    const float* b3 = (const float*)d_in[6];
    const int* ei  = (const int*)d_in[7];
    const int* eli = (const int*)d_in[8];

    const int n  = in_sizes[0] / 128;
    const int E  = in_sizes[7] / 2;
    const int EL = in_sizes[8] / 2;
    float* out = (float*)d_out;

    const int* esrc = ei;
    const int* edst = ei + E;

    const long nh = (long)n * HID;
    const int nBlk  = (n + 255) / 256;
    const int eBlk  = (E + 255) / 256;
    const int gBlk  = (n + 31) / 32;
    const int aBlk  = (n + 3) / 4;
    const int nb = (n + BN - 1) >> BSH;
    const int chunk = (E + PB - 1) / PB;

    // -------- workspace layout (bf16 main path) --------
    size_t o = 0;
    char* ws = (char*)d_ws;
    int*   table  = (int*)(ws + o); o += alignup((size_t)MAXNB * PB * 4);
    int*   rowsum = (int*)(ws + o); o += alignup((size_t)MAXNB * 4);
    int*   deg    = (int*)(ws + o); o += alignup((size_t)n * 4);
    float* dinv   = (float*)(ws + o); o += alignup((size_t)n * 4);
    int*   ell    = (int*)(ws + o); o += alignup((size_t)n * ELLW * 4);
    bfraw* bufA   = (bfraw*)(ws + o); o += alignup((nh + HID) * 2);   // +1 zero pad row
    bfraw* bufB   = (bfraw*)(ws + o); o += alignup((nh + HID) * 2);
    const size_t need_main = o;
    int* part = (int*)bufA;  // E ints (E*4 bytes) <= (nh+HID)*2 bytes; dead before gemm writes bufA

    if (n <= (1 << SRCBITS) && nb <= MAXNB && (long)E * 2 <= nh + HID && ws_size >= need_main) {
        // ---- build: contention-free two-pass partition + per-bucket ELL ----
        k_hist<<<PB, 256, 0, stream>>>(edst, table, E, nb, chunk);
        k_scanA<<<nb, PB, 0, stream>>>(table, rowsum);
        k_scanB<<<1, PB, 0, stream>>>(rowsum, nb);
        k_scanC<<<(nb * PB + 255) / 256, 256, 0, stream>>>(table, rowsum, nb * PB);
        k_pscatter<<<PB, 256, 0, stream>>>(esrc, edst, table, part, E, nb, chunk);
        k_bell<<<nb, 256, 0, stream>>>(part, table, ell, deg, dinv, E, nb, n);
        k_zero_padrow<<<1, 64, 0, stream>>>(bufA, bufB, nh);

        // ---- layers (bf16 staged features, fp32 math) ----
        k_gemm_bf<128><<<gBlk, 256, 0, stream>>>(x, W1, dinv, bufA, n);              // g1 (kills part)
        k_aggb<true ><<<aBlk, 256, 0, stream>>>(deg, ell, bufA, dinv, b1, W2, bufB, n); // g2
        k_aggb<true ><<<aBlk, 256, 0, stream>>>(deg, ell, bufB, dinv, b2, W3, bufA, n); // g3
        k_aggb<false><<<aBlk, 256, 0, stream>>>(deg, ell, bufA, dinv, b3, (const float*)0, bufB, n); // h3

        k_score_bf<<<(EL + 31) / 32, 256, 0, stream>>>(eli, eli + EL, bufB, out, EL);
    } else {
        // -------- fallback: proven r3 fp32 single-pass ELL path --------
        size_t o2 = 0;
        int*   cur   = (int*)(ws + o2);   o2 += alignup((size_t)n * 4);
        float* dinv2 = (float*)(ws + o2); o2 += alignup((size_t)n * 4);
        int*   ell2  = (int*)(ws + o2);   o2 += alignup((size_t)n * ELLW * 4);
        float* fA    = (float*)(ws + o2); o2 += alignup(nh * 4);
        float* fB    = (float*)(ws + o2); o2 += alignup(nh * 4);

        k_zero_int<<<nBlk, 256, 0, stream>>>(cur, n);
        k_ell_fill<<<eBlk, 256, 0, stream>>>(esrc, edst, cur, ell2, E);
        k_dinv_from_deg<<<nBlk, 256, 0, stream>>>(cur, dinv2, n);

        k_gemm_f32<128><<<gBlk, 256, 0, stream>>>(x, W1, dinv2, fA, n);
        k_agg_gemm<<<aBlk, 256, 0, stream>>>(cur, ell2, fA, dinv2, b1, W2, fB, n);
        k_agg_gemm<<<aBlk, 256, 0, stream>>>(cur, ell2, fB, dinv2, b2, W3, fA, n);
        k_aggregate_ell<<<aBlk, 256, 0, stream>>>(cur, ell2, fA, fB, dinv2, b3, n);

        k_score_f32<<<(int)(((long)EL * 16 + 255) / 256), 256, 0, stream>>>(eli, eli + EL, fA, out, EL);
    }
}

// Round 9
// 350.371 us; speedup vs baseline: 12.2002x; 1.2819x over previous
//
#include <hip/hip_runtime.h>
#include <math.h>

#define HID 64
#define BSH 8                      // 256 nodes per bucket
#define BN 256
#define SRCBITS 17
#define SRCMASK ((1 << SRCBITS) - 1)
#define PB 512                     // partition chunks
#define MAXNB 512                  // max buckets (n <= 131072)
#define ELLW 96

typedef unsigned short bfraw;      // raw bf16 storage

__device__ __forceinline__ float bf_lo(unsigned u) { return __uint_as_float(u << 16); }
__device__ __forceinline__ float bf_hi(unsigned u) { return __uint_as_float(u & 0xffff0000u); }
__device__ __forceinline__ unsigned short f2bf(float f) {
    unsigned u = __float_as_uint(f);
    u += 0x7fffu + ((u >> 16) & 1u);   // round-to-nearest-even (finite values)
    return (unsigned short)(u >> 16);
}
__device__ __forceinline__ unsigned pack2(float a, float b) {
    return (unsigned)f2bf(a) | ((unsigned)f2bf(b) << 16);
}

// acc[c] += sum_j xv[j] * wj[c]   (wj = W rows k..k+3, channels cq*4..+3)
__device__ __forceinline__ void fma4x4(float4& acc, const float4 xv,
                                       const float4 w0, const float4 w1,
                                       const float4 w2, const float4 w3) {
    acc.x = fmaf(xv.x, w0.x, acc.x); acc.y = fmaf(xv.x, w0.y, acc.y);
    acc.z = fmaf(xv.x, w0.z, acc.z); acc.w = fmaf(xv.x, w0.w, acc.w);
    acc.x = fmaf(xv.y, w1.x, acc.x); acc.y = fmaf(xv.y, w1.y, acc.y);
    acc.z = fmaf(xv.y, w1.z, acc.z); acc.w = fmaf(xv.y, w1.w, acc.w);
    acc.x = fmaf(xv.z, w2.x, acc.x); acc.y = fmaf(xv.z, w2.y, acc.y);
    acc.z = fmaf(xv.z, w2.z, acc.z); acc.w = fmaf(xv.z, w2.w, acc.w);
    acc.x = fmaf(xv.w, w3.x, acc.x); acc.y = fmaf(xv.w, w3.y, acc.y);
    acc.z = fmaf(xv.w, w3.z, acc.z); acc.w = fmaf(xv.w, w3.w, acc.w);
}

// ================= small utility =================
__global__ void k_zero_int(int* __restrict__ p, int n) {
    int i = blockIdx.x * blockDim.x + threadIdx.x;
    if (i < n) p[i] = 0;
}

__global__ void k_zero_padrow(bfraw* __restrict__ a, bfraw* __restrict__ b, long off) {
    int t = threadIdx.x;
    if (t < HID) { a[off + t] = 0; b[off + t] = 0; }
}

// ================= P1: per-chunk bucket histogram =================
__global__ void k_hist(const int* __restrict__ dst, int* __restrict__ table,
                       int E, int nb, int chunk) {
    __shared__ int lh[MAXNB];
    for (int t = threadIdx.x; t < nb; t += 256) lh[t] = 0;
    __syncthreads();
    int beg = blockIdx.x * chunk;
    int end = beg + chunk; if (end > E) end = E;
    for (int e = beg + threadIdx.x; e < end; e += 256)
        atomicAdd(&lh[dst[e] >> BSH], 1);
    __syncthreads();
    for (int t = threadIdx.x; t < nb; t += 256)
        table[t * PB + blockIdx.x] = lh[t];
}

// ================= P2a: per-bucket exclusive scan across chunks =================
__global__ void k_scanA(int* __restrict__ table, int* __restrict__ rowsum) {
    __shared__ int lds[PB];
    const int bu = blockIdx.x;
    const int t = threadIdx.x;
    int v = table[bu * PB + t];
    lds[t] = v;
    __syncthreads();
    for (int off = 1; off < PB; off <<= 1) {
        int u = (t >= off) ? lds[t - off] : 0;
        __syncthreads();
        lds[t] += u;
        __syncthreads();
    }
    table[bu * PB + t] = lds[t] - v;
    if (t == PB - 1) rowsum[bu] = lds[t];
}

// ================= P2b: exclusive scan of bucket totals =================
__global__ void k_scanB(int* __restrict__ rowsum, int nb) {
    __shared__ int lds[PB];
    const int t = threadIdx.x;
    int v = (t < nb) ? rowsum[t] : 0;
    lds[t] = v;
    __syncthreads();
    for (int off = 1; off < PB; off <<= 1) {
        int u = (t >= off) ? lds[t - off] : 0;
        __syncthreads();
        lds[t] += u;
        __syncthreads();
    }
    if (t < nb) rowsum[t] = lds[t] - v;
}

// ================= P2c: add bucket base =================
__global__ void k_scanC(int* __restrict__ table, const int* __restrict__ rowsum, int L) {
    int i = blockIdx.x * 256 + threadIdx.x;
    if (i < L) table[i] += rowsum[i >> 9];  // i / PB, PB=512
}

// ================= P3: partition scatter =================
__global__ void k_pscatter(const int* __restrict__ src, const int* __restrict__ dst,
                           const int* __restrict__ excl, int* __restrict__ part,
                           int E, int nb, int chunk) {
    __shared__ int cur[MAXNB];
    for (int t = threadIdx.x; t < nb; t += 256) cur[t] = excl[t * PB + blockIdx.x];
    __syncthreads();
    int beg = blockIdx.x * chunk;
    int end = beg + chunk; if (end > E) end = E;
    for (int e = beg + threadIdx.x; e < end; e += 256) {
        int d = dst[e];
        int bu = d >> BSH;
        int pos = atomicAdd(&cur[bu], 1);
        part[pos] = ((d & (BN - 1)) << SRCBITS) | src[e];
    }
}

// ================= P4: per-bucket ELL fill + degree + dinv + pad-to-8 =================
__global__ void k_bell(const int* __restrict__ part, const int* __restrict__ excl,
                       int* __restrict__ ell, int* __restrict__ deg,
                       float* __restrict__ dinv, int E, int nb, int n) {
    __shared__ int cnt[BN];
    int b = blockIdx.x;
    for (int t = threadIdx.x; t < BN; t += 256) cnt[t] = 0;
    __syncthreads();
    int beg = excl[b * PB];
    int end = (b == nb - 1) ? E : excl[(b + 1) * PB];
    for (int i = beg + threadIdx.x; i < end; i += 256) {
        int c = part[i];
        int dl = c >> SRCBITS;
        int p = atomicAdd(&cnt[dl], 1);
        if (p < ELLW) ell[(size_t)((b << BSH) + dl) * ELLW + p] = c & SRCMASK;
    }
    __syncthreads();
    for (int t = threadIdx.x; t < BN; t += 256) {
        int node = (b << BSH) + t;
        if (node < n) {
            int dgv = cnt[t];
            int len = dgv < ELLW ? dgv : ELLW;
            int len8 = (len + 7) & ~7;      // ELLW%8==0 so len8<=ELLW
            int* r = ell + (size_t)node * ELLW;
            for (int p = len; p < len8; ++p) r[p] = n;   // pad -> zero row
            deg[node] = dgv;
            dinv[node] = rsqrtf((float)(dgv + 1));
        }
    }
}

// ================= GEMM + dinv scale -> bf16 (b128 W reads, 4-row x 4-ch register tile) ========
// lane = cq(16 chan-quads) x rq(4 row-groups); each lane: rows base..base+3, channels cq*4..+3
template<int K>
__launch_bounds__(256)
__global__ void k_gemm_bf(const float* __restrict__ x, const float* __restrict__ W,
                          const float* __restrict__ dinv, bfraw* __restrict__ g, int n) {
    __shared__ float sW[K * HID];
    for (int t = threadIdx.x; t < K * HID / 4; t += 256)
        ((float4*)sW)[t] = ((const float4*)W)[t];
    __syncthreads();
    const int wv = threadIdx.x >> 6;
    const int lane = threadIdx.x & 63;
    const int cq = lane & 15;
    const int rq = lane >> 4;
    const int base = blockIdx.x * 64 + wv * 16 + rq * 4;
    if (base >= n) return;
    if (base + 3 < n) {
        const float* xr = x + (size_t)base * K;
        float4 a0 = {0,0,0,0}, a1 = {0,0,0,0}, a2 = {0,0,0,0}, a3 = {0,0,0,0};
#pragma unroll 2
        for (int k = 0; k < K; k += 4) {
            float4 x0 = *(const float4*)(xr + k);
            float4 x1 = *(const float4*)(xr + K + k);
            float4 x2 = *(const float4*)(xr + 2 * K + k);
            float4 x3 = *(const float4*)(xr + 3 * K + k);
            const float* wp = sW + k * HID + cq * 4;
            float4 w0 = *(const float4*)(wp);
            float4 w1 = *(const float4*)(wp + HID);
            float4 w2 = *(const float4*)(wp + 2 * HID);
            float4 w3 = *(const float4*)(wp + 3 * HID);
            fma4x4(a0, x0, w0, w1, w2, w3);
            fma4x4(a1, x1, w0, w1, w2, w3);
            fma4x4(a2, x2, w0, w1, w2, w3);
            fma4x4(a3, x3, w0, w1, w2, w3);
        }
        float d0 = dinv[base], d1 = dinv[base + 1], d2 = dinv[base + 2], d3 = dinv[base + 3];
        uint2 o;
        o.x = pack2(a0.x * d0, a0.y * d0); o.y = pack2(a0.z * d0, a0.w * d0);
        *(uint2*)(g + (size_t)(base + 0) * HID + cq * 4) = o;
        o.x = pack2(a1.x * d1, a1.y * d1); o.y = pack2(a1.z * d1, a1.w * d1);
        *(uint2*)(g + (size_t)(base + 1) * HID + cq * 4) = o;
        o.x = pack2(a2.x * d2, a2.y * d2); o.y = pack2(a2.z * d2, a2.w * d2);
        *(uint2*)(g + (size_t)(base + 2) * HID + cq * 4) = o;
        o.x = pack2(a3.x * d3, a3.y * d3); o.y = pack2(a3.z * d3, a3.w * d3);
        *(uint2*)(g + (size_t)(base + 3) * HID + cq * 4) = o;
    } else {
        for (int r = 0; r < 4; ++r) {
            int row = base + r;
            if (row >= n) break;
            const float* xp = x + (size_t)row * K;
            float4 acc = {0,0,0,0};
            for (int k = 0; k < K; k += 4) {
                float4 xv = *(const float4*)(xp + k);
                const float* wp = sW + k * HID + cq * 4;
                float4 w0 = *(const float4*)(wp);
                float4 w1 = *(const float4*)(wp + HID);
                float4 w2 = *(const float4*)(wp + 2 * HID);
                float4 w3 = *(const float4*)(wp + 3 * HID);
                fma4x4(acc, xv, w0, w1, w2, w3);
            }
            float di = dinv[row];
            uint2 o;
            o.x = pack2(acc.x * di, acc.y * di); o.y = pack2(acc.z * di, acc.w * di);
            *(uint2*)(g + (size_t)row * HID + cq * 4) = o;
        }
    }
}

// ================= bf16 aggregation: 8-lane uint4 groups, 8 edges per wave-load =================
// FUSE epilogue retiled: lane = cq2(16 chan-quads) x kq(4 k-quarters), b128 W reads, shfl reduce.
template<bool FUSE>
__launch_bounds__(256)
__global__ void k_aggb(const int* __restrict__ deg, const int* __restrict__ ell,
                       const bfraw* __restrict__ g, const float* __restrict__ dinv,
                       const float* __restrict__ bias, const float* __restrict__ Wn,
                       bfraw* __restrict__ outp, int n) {
    __shared__ float sW[FUSE ? HID * HID : 4];
    __shared__ float sH[4][HID];
    if (FUSE) {
        for (int t = threadIdx.x; t < HID * HID / 4; t += 256)
            ((float4*)sW)[t] = ((const float4*)Wn)[t];
    }
    const int wv = threadIdx.x >> 6;
    const int lane = threadIdx.x & 63;
    const int grp = lane >> 3;
    const int cq = lane & 7;
    const int node = blockIdx.x * 4 + wv;
    float a0 = 0, a1 = 0, a2 = 0, a3 = 0, a4 = 0, a5 = 0, a6 = 0, a7 = 0;
    if (node < n) {
        int dg = deg[node];
        int len = dg < ELLW ? dg : ELLW;
        int len8 = (len + 7) & ~7;
        const int* row = ell + (size_t)node * ELLW;
        int j = grp;
        for (; j + 8 < len8; j += 16) {      // pair {j, j+8}: 16 wave-edges in flight
            int s0 = row[j];
            int s1 = row[j + 8];
            const uint4 v0 = *(const uint4*)(g + (size_t)s0 * HID + cq * 8);
            const uint4 v1 = *(const uint4*)(g + (size_t)s1 * HID + cq * 8);
            a0 += bf_lo(v0.x) + bf_lo(v1.x);
            a1 += bf_hi(v0.x) + bf_hi(v1.x);
            a2 += bf_lo(v0.y) + bf_lo(v1.y);
            a3 += bf_hi(v0.y) + bf_hi(v1.y);
            a4 += bf_lo(v0.z) + bf_lo(v1.z);
            a5 += bf_hi(v0.z) + bf_hi(v1.z);
            a6 += bf_lo(v0.w) + bf_lo(v1.w);
            a7 += bf_hi(v0.w) + bf_hi(v1.w);
        }
        for (; j < len8; j += 8) {
            int s0 = row[j];
            const uint4 v0 = *(const uint4*)(g + (size_t)s0 * HID + cq * 8);
            a0 += bf_lo(v0.x); a1 += bf_hi(v0.x);
            a2 += bf_lo(v0.y); a3 += bf_hi(v0.y);
            a4 += bf_lo(v0.z); a5 += bf_hi(v0.z);
            a6 += bf_lo(v0.w); a7 += bf_hi(v0.w);
        }
    }
    a0 += __shfl_xor(a0, 8);  a1 += __shfl_xor(a1, 8);  a2 += __shfl_xor(a2, 8);  a3 += __shfl_xor(a3, 8);
    a4 += __shfl_xor(a4, 8);  a5 += __shfl_xor(a5, 8);  a6 += __shfl_xor(a6, 8);  a7 += __shfl_xor(a7, 8);
    a0 += __shfl_xor(a0, 16); a1 += __shfl_xor(a1, 16); a2 += __shfl_xor(a2, 16); a3 += __shfl_xor(a3, 16);
    a4 += __shfl_xor(a4, 16); a5 += __shfl_xor(a5, 16); a6 += __shfl_xor(a6, 16); a7 += __shfl_xor(a7, 16);
    a0 += __shfl_xor(a0, 32); a1 += __shfl_xor(a1, 32); a2 += __shfl_xor(a2, 32); a3 += __shfl_xor(a3, 32);
    a4 += __shfl_xor(a4, 32); a5 += __shfl_xor(a5, 32); a6 += __shfl_xor(a6, 32); a7 += __shfl_xor(a7, 32);
    if (node < n && grp == 0) {
        const uint4 sv = *(const uint4*)(g + (size_t)node * HID + cq * 8);
        float di = dinv[node];
        const float4 bv0 = *(const float4*)(bias + cq * 8);
        const float4 bv1 = *(const float4*)(bias + cq * 8 + 4);
        float h0 = di * (a0 + bf_lo(sv.x)) + bv0.x;
        float h1 = di * (a1 + bf_hi(sv.x)) + bv0.y;
        float h2 = di * (a2 + bf_lo(sv.y)) + bv0.z;
        float h3 = di * (a3 + bf_hi(sv.y)) + bv0.w;
        float h4 = di * (a4 + bf_lo(sv.z)) + bv1.x;
        float h5 = di * (a5 + bf_hi(sv.z)) + bv1.y;
        float h6 = di * (a6 + bf_lo(sv.w)) + bv1.z;
        float h7 = di * (a7 + bf_hi(sv.w)) + bv1.w;
        if (!FUSE) {
            uint4 o;
            o.x = pack2(h0, h1); o.y = pack2(h2, h3);
            o.z = pack2(h4, h5); o.w = pack2(h6, h7);
            *(uint4*)(outp + (size_t)node * HID + cq * 8) = o;
        } else {
            h0 = fmaxf(h0, 0.0f); h1 = fmaxf(h1, 0.0f); h2 = fmaxf(h2, 0.0f); h3 = fmaxf(h3, 0.0f);
            h4 = fmaxf(h4, 0.0f); h5 = fmaxf(h5, 0.0f); h6 = fmaxf(h6, 0.0f); h7 = fmaxf(h7, 0.0f);
            *(float4*)(&sH[wv][cq * 8])     = make_float4(h0, h1, h2, h3);
            *(float4*)(&sH[wv][cq * 8 + 4]) = make_float4(h4, h5, h6, h7);
        }
    }
    if (FUSE) {
        __syncthreads();   // covers sW staging + sH visibility
        if (node < n) {
            const float* hr = sH[wv];
            const int cq2 = lane & 15;         // channels cq2*4..+3
            const int kq = lane >> 4;          // k-range kq*16..+15
            float4 acc = {0,0,0,0};
#pragma unroll
            for (int kk = 0; kk < 16; kk += 4) {
                int k = kq * 16 + kk;
                float4 hv = *(const float4*)(hr + k);
                const float* wp = sW + k * HID + cq2 * 4;
                float4 w0 = *(const float4*)(wp);
                float4 w1 = *(const float4*)(wp + HID);
                float4 w2 = *(const float4*)(wp + 2 * HID);
                float4 w3 = *(const float4*)(wp + 3 * HID);
                fma4x4(acc, hv, w0, w1, w2, w3);
            }
            acc.x += __shfl_xor(acc.x, 16); acc.y += __shfl_xor(acc.y, 16);
            acc.z += __shfl_xor(acc.z, 16); acc.w += __shfl_xor(acc.w, 16);
            acc.x += __shfl_xor(acc.x, 32); acc.y += __shfl_xor(acc.y, 32);
            acc.z += __shfl_xor(acc.z, 32); acc.w += __shfl_xor(acc.w, 32);
            if (kq == 0) {
                float di = dinv[node];
                uint2 o;
                o.x = pack2(acc.x * di, acc.y * di);
                o.y = pack2(acc.z * di, acc.w * di);
                *(uint2*)(outp + (size_t)node * HID + cq2 * 4) = o;
            }
        }
    }
}

// ================= link scores from bf16 h3: 8 lanes/edge =================
__launch_bounds__(256)
__global__ void k_score_bf(const int* __restrict__ ls, const int* __restrict__ ld,
                           const bfraw* __restrict__ h, float* __restrict__ out, int EL) {
    const int wv = threadIdx.x >> 6;
    const int lane = threadIdx.x & 63;
    const int grp = lane >> 3;
    const int cq = lane & 7;
    long e = (long)blockIdx.x * 32 + wv * 8 + grp;
    if (e >= EL) return;   // group-uniform
    int s = ls[e];
    int d = ld[e];
    const uint4 va = *(const uint4*)(h + (size_t)s * HID + cq * 8);
    const uint4 vb = *(const uint4*)(h + (size_t)d * HID + cq * 8);
    float p = bf_lo(va.x) * bf_lo(vb.x) + bf_hi(va.x) * bf_hi(vb.x)
            + bf_lo(va.y) * bf_lo(vb.y) + bf_hi(va.y) * bf_hi(vb.y)
            + bf_lo(va.z) * bf_lo(vb.z) + bf_hi(va.z) * bf_hi(vb.z)
            + bf_lo(va.w) * bf_lo(vb.w) + bf_hi(va.w) * bf_hi(vb.w);
    p += __shfl_xor(p, 1);
    p += __shfl_xor(p, 2);
    p += __shfl_xor(p, 4);
    if (cq == 0) out[e] = 1.0f / (1.0f + __expf(-p));
}

// ================= fallback: proven r3 fp32 kernels =================
__global__ void k_ell_fill(const int* __restrict__ src, const int* __restrict__ dst,
                           int* __restrict__ cur, int* __restrict__ ell, int E) {
    int e = blockIdx.x * blockDim.x + threadIdx.x;
    if (e < E) {
        int d = dst[e];
        int p = atomicAdd(&cur[d], 1);
        if (p < ELLW) ell[(size_t)d * ELLW + p] = src[e];
    }
}
__global__ void k_dinv_from_deg(const int* __restrict__ deg, float* __restrict__ dinv, int n) {
    int i = blockIdx.x * blockDim.x + threadIdx.x;
    if (i < n) dinv[i] = rsqrtf((float)(deg[i] + 1));
}
template<int K>
__launch_bounds__(256)
__global__ void k_gemm_f32(const float* __restrict__ x, const float* __restrict__ W,
                           const float* __restrict__ dinv, float* __restrict__ g, int n) {
    __shared__ float sW[K * HID];
    for (int t = threadIdx.x; t < K * HID; t += 256) sW[t] = W[t];
    __syncthreads();
    const int lane = threadIdx.x & 63;
    const int rowInBlk = threadIdx.x >> 6;
    const int ROWS = 32;
    const int base = blockIdx.x * ROWS;
    for (int r = rowInBlk; r < ROWS; r += 4) {
        int i = base + r;
        if (i >= n) return;
        const float* xr = x + (size_t)i * K;
        float acc = 0.0f;
#pragma unroll
        for (int k = 0; k < K; k += 4) {
            float4 xv = *(const float4*)(xr + k);
            acc = fmaf(xv.x, sW[(k + 0) * HID + lane], acc);
            acc = fmaf(xv.y, sW[(k + 1) * HID + lane], acc);
            acc = fmaf(xv.z, sW[(k + 2) * HID + lane], acc);
            acc = fmaf(xv.w, sW[(k + 3) * HID + lane], acc);
        }
        g[(size_t)i * HID + lane] = acc * dinv[i];
    }
}
__launch_bounds__(256)
__global__ void k_agg_gemm(const int* __restrict__ deg, const int* __restrict__ ell,
                           const float* __restrict__ g, const float* __restrict__ dinv,
                           const float* __restrict__ bias, const float* __restrict__ Wn,
                           float* __restrict__ gout, int n) {
    __shared__ float sW[HID * HID];
    __shared__ float sH[4][HID];
    for (int t = threadIdx.x; t < HID * HID; t += 256) sW[t] = Wn[t];
    const int wv = threadIdx.x >> 6;
    const int lane = threadIdx.x & 63;
    const int node = blockIdx.x * 4 + wv;
    if (node < n) {
        int dg = deg[node];
        int len = dg < ELLW ? dg : ELLW;
        const int* row = ell + (size_t)node * ELLW;
        float acc = g[(size_t)node * HID + lane];
        int j = 0;
        for (; j + 4 <= len; j += 4) {
            int s0 = row[j], s1 = row[j + 1], s2 = row[j + 2], s3 = row[j + 3];
            acc += (g[(size_t)s0 * HID + lane] + g[(size_t)s1 * HID + lane]) +
                   (g[(size_t)s2 * HID + lane] + g[(size_t)s3 * HID + lane]);
        }
        for (; j < len; ++j) acc += g[(size_t)row[j] * HID + lane];
        float h = fmaxf(dinv[node] * acc + bias[lane], 0.0f);
        sH[wv][lane] = h;
    }
    __syncthreads();
    if (node < n) {
        const float* hr = sH[wv];
        float o = 0.0f;
#pragma unroll
        for (int k = 0; k < HID; k += 4) {
            o = fmaf(hr[k + 0], sW[(k + 0) * HID + lane], o);
            o = fmaf(hr[k + 1], sW[(k + 1) * HID + lane], o);
            o = fmaf(hr[k + 2], sW[(k + 2) * HID + lane], o);
            o = fmaf(hr[k + 3], sW[(k + 3) * HID + lane], o);
        }
        gout[(size_t)node * HID + lane] = o * dinv[node];
    }
}
__launch_bounds__(256)
__global__ void k_aggregate_ell(const int* __restrict__ deg, const int* __restrict__ ell,
                                const float* __restrict__ g, float* __restrict__ out,
                                const float* __restrict__ dinv, const float* __restrict__ b,
                                int n) {
    int node = (int)(((long)blockIdx.x * 256 + threadIdx.x) >> 6);
    int lane = threadIdx.x & 63;
    if (node >= n) return;
    int dg = deg[node];
    int len = dg < ELLW ? dg : ELLW;
    const int* row = ell + (size_t)node * ELLW;
    float acc = g[(size_t)node * HID + lane];
    int j = 0;
    for (; j + 4 <= len; j += 4) {
        int s0 = row[j], s1 = row[j + 1], s2 = row[j + 2], s3 = row[j + 3];
        acc += (g[(size_t)s0 * HID + lane] + g[(size_t)s1 * HID + lane]) +
               (g[(size_t)s2 * HID + lane] + g[(size_t)s3 * HID + lane]);
    }
    for (; j < len; ++j) acc += g[(size_t)row[j] * HID + lane];
    out[(size_t)node * HID + lane] = dinv[node] * acc + b[lane];
}
__launch_bounds__(256)
__global__ void k_score_f32(const int* __restrict__ ls, const int* __restrict__ ld,
                            const float* __restrict__ h, float* __restrict__ out, int EL) {
    long t = (long)blockIdx.x * 256 + threadIdx.x;
    long e = t >> 4;
    if (e >= EL) return;
    int q = (int)(t & 15);
    int s = ls[e];
    int d = ld[e];
    float4 a  = *(const float4*)(h + (size_t)s * HID + q * 4);
    float4 bb = *(const float4*)(h + (size_t)d * HID + q * 4);
    float p = a.x * bb.x + a.y * bb.y + a.z * bb.z + a.w * bb.w;
    p += __shfl_xor(p, 1);
    p += __shfl_xor(p, 2);
    p += __shfl_xor(p, 4);
    p += __shfl_xor(p, 8);
    if (q == 0) out[e] = 1.0f / (1.0f + __expf(-p));
}

static inline size_t alignup(size_t v) { return (v + 255) & ~(size_t)255; }

extern "C" void kernel_launch(void* const* d_in, const int* in_sizes, int n_in,
                              void* d_out, int out_size, void* d_ws, size_t ws_size,
                              hipStream_t stream) {
    const float* x  = (const float*)d_in[0];
    const float* W1 = (const float*)d_in[1];
    const float* b1 = (const float*)d_in[2];
    const float* W2 = (const float*)d_in[3];
    const float* b2 = (const float*)d_in[4];
    const float* W3 = (const float*)d_in[5];
    const float* b3 = (const float*)d_in[6];
    const int* ei  = (const int*)d_in[7];
    const int* eli = (const int*)d_in[8];

    const int n  = in_sizes[0] / 128;
    const int E  = in_sizes[7] / 2;
    const int EL = in_sizes[8] / 2;
    float* out = (float*)d_out;

    const int* esrc = ei;
    const int* edst = ei + E;

    const long nh = (long)n * HID;
    const int nBlk  = (n + 255) / 256;
    const int eBlk  = (E + 255) / 256;
    const int aBlk  = (n + 3) / 4;
    const int nb = (n + BN - 1) >> BSH;
    const int chunk = (E + PB - 1) / PB;

    // -------- workspace layout (bf16 main path) --------
    size_t o = 0;
    char* ws = (char*)d_ws;
    int*   table  = (int*)(ws + o); o += alignup((size_t)MAXNB * PB * 4);
    int*   rowsum = (int*)(ws + o); o += alignup((size_t)MAXNB * 4);
    int*   deg    = (int*)(ws + o); o += alignup((size_t)n * 4);
    float* dinv   = (float*)(ws + o); o += alignup((size_t)n * 4);
    int*   ell    = (int*)(ws + o); o += alignup((size_t)n * ELLW * 4);
    bfraw* bufA   = (bfraw*)(ws + o); o += alignup((nh + HID) * 2);   // +1 zero pad row
    bfraw* bufB   = (bfraw*)(ws + o); o += alignup((nh + HID) * 2);
    const size_t need_main = o;
    int* part = (int*)bufA;  // E ints <= (nh+HID)*2 bytes; dead before gemm writes bufA

    if (n <= (1 << SRCBITS) && nb <= MAXNB && (long)E * 2 <= nh + HID && ws_size >= need_main) {
        // ---- build: contention-free two-pass partition + per-bucket ELL ----
        k_hist<<<PB, 256, 0, stream>>>(edst, table, E, nb, chunk);
        k_scanA<<<nb, PB, 0, stream>>>(table, rowsum);
        k_scanB<<<1, PB, 0, stream>>>(rowsum, nb);
        k_scanC<<<(nb * PB + 255) / 256, 256, 0, stream>>>(table, rowsum, nb * PB);
        k_pscatter<<<PB, 256, 0, stream>>>(esrc, edst, table, part, E, nb, chunk);
        k_bell<<<nb, 256, 0, stream>>>(part, table, ell, deg, dinv, E, nb, n);
        k_zero_padrow<<<1, 64, 0, stream>>>(bufA, bufB, nh);

        // ---- layers (bf16 staged features, fp32 math) ----
        k_gemm_bf<128><<<(n + 63) / 64, 256, 0, stream>>>(x, W1, dinv, bufA, n);     // g1 (kills part)
        k_aggb<true ><<<aBlk, 256, 0, stream>>>(deg, ell, bufA, dinv, b1, W2, bufB, n); // g2
        k_aggb<true ><<<aBlk, 256, 0, stream>>>(deg, ell, bufB, dinv, b2, W3, bufA, n); // g3
        k_aggb<false><<<aBlk, 256, 0, stream>>>(deg, ell, bufA, dinv, b3, (const float*)0, bufB, n); // h3

        k_score_bf<<<(EL + 31) / 32, 256, 0, stream>>>(eli, eli + EL, bufB, out, EL);
    } else {
        // -------- fallback: proven r3 fp32 single-pass ELL path --------
        size_t o2 = 0;
        int*   cur   = (int*)(ws + o2);   o2 += alignup((size_t)n * 4);
        float* dinv2 = (float*)(ws + o2); o2 += alignup((size_t)n * 4);
        int*   ell2  = (int*)(ws + o2);   o2 += alignup((size_t)n * ELLW * 4);
        float* fA    = (float*)(ws + o2); o2 += alignup(nh * 4);
        float* fB    = (float*)(ws + o2); o2 += alignup(nh * 4);

        k_zero_int<<<nBlk, 256, 0, stream>>>(cur, n);
        k_ell_fill<<<eBlk, 256, 0, stream>>>(esrc, edst, cur, ell2, E);
        k_dinv_from_deg<<<nBlk, 256, 0, stream>>>(cur, dinv2, n);

        k_gemm_f32<128><<<(n + 31) / 32, 256, 0, stream>>>(x, W1, dinv2, fA, n);
        k_agg_gemm<<<aBlk, 256, 0, stream>>>(cur, ell2, fA, dinv2, b1, W2, fB, n);
        k_agg_gemm<<<aBlk, 256, 0, stream>>>(cur, ell2, fB, dinv2, b2, W3, fA, n);
        k_aggregate_ell<<<aBlk, 256, 0, stream>>>(cur, ell2, fA, fB, dinv2, b3, n);

        k_score_f32<<<(int)(((long)EL * 16 + 255) / 256), 256, 0, stream>>>(eli, eli + EL, fA, out, EL);
    }
}

// Round 10
// 305.849 us; speedup vs baseline: 13.9762x; 1.1456x over previous
//
#include <hip/hip_runtime.h>
#include <math.h>

#define HID 64
#define BSH 8                      // 256 nodes per bucket
#define BN 256
#define SRCBITS 17
#define SRCMASK ((1 << SRCBITS) - 1)
#define PB 512                     // partition chunks
#define MAXNB 512                  // max buckets (n <= 131072)
#define ELLW 96

typedef unsigned short bfraw;      // raw bf16 storage

__device__ __forceinline__ float bf_lo(unsigned u) { return __uint_as_float(u << 16); }
__device__ __forceinline__ float bf_hi(unsigned u) { return __uint_as_float(u & 0xffff0000u); }
__device__ __forceinline__ unsigned short f2bf(float f) {
    unsigned u = __float_as_uint(f);
    u += 0x7fffu + ((u >> 16) & 1u);   // round-to-nearest-even (finite values)
    return (unsigned short)(u >> 16);
}
__device__ __forceinline__ unsigned pack2(float a, float b) {
    return (unsigned)f2bf(a) | ((unsigned)f2bf(b) << 16);
}

// acc[c] += sum_j xv[j] * wj[c]
__device__ __forceinline__ void fma4x4(float4& acc, const float4 xv,
                                       const float4 w0, const float4 w1,
                                       const float4 w2, const float4 w3) {
    acc.x = fmaf(xv.x, w0.x, acc.x); acc.y = fmaf(xv.x, w0.y, acc.y);
    acc.z = fmaf(xv.x, w0.z, acc.z); acc.w = fmaf(xv.x, w0.w, acc.w);
    acc.x = fmaf(xv.y, w1.x, acc.x); acc.y = fmaf(xv.y, w1.y, acc.y);
    acc.z = fmaf(xv.y, w1.z, acc.z); acc.w = fmaf(xv.y, w1.w, acc.w);
    acc.x = fmaf(xv.z, w2.x, acc.x); acc.y = fmaf(xv.z, w2.y, acc.y);
    acc.z = fmaf(xv.z, w2.z, acc.z); acc.w = fmaf(xv.z, w2.w, acc.w);
    acc.x = fmaf(xv.w, w3.x, acc.x); acc.y = fmaf(xv.w, w3.y, acc.y);
    acc.z = fmaf(xv.w, w3.z, acc.z); acc.w = fmaf(xv.w, w3.w, acc.w);
}

// ================= small utility =================
__global__ void k_zero_int(int* __restrict__ p, int n) {
    int i = blockIdx.x * blockDim.x + threadIdx.x;
    if (i < n) p[i] = 0;
}

__global__ void k_zero_padrow(bfraw* __restrict__ a, bfraw* __restrict__ b, long off) {
    int t = threadIdx.x;
    if (t < HID) { a[off + t] = 0; b[off + t] = 0; }
}

// ================= P1: per-chunk bucket histogram =================
__global__ void k_hist(const int* __restrict__ dst, int* __restrict__ table,
                       int E, int nb, int chunk) {
    __shared__ int lh[MAXNB];
    for (int t = threadIdx.x; t < nb; t += 256) lh[t] = 0;
    __syncthreads();
    int beg = blockIdx.x * chunk;
    int end = beg + chunk; if (end > E) end = E;
    for (int e = beg + threadIdx.x; e < end; e += 256)
        atomicAdd(&lh[dst[e] >> BSH], 1);
    __syncthreads();
    for (int t = threadIdx.x; t < nb; t += 256)
        table[t * PB + blockIdx.x] = lh[t];
}

// ================= P2a: per-bucket exclusive scan across chunks =================
__global__ void k_scanA(int* __restrict__ table, int* __restrict__ rowsum) {
    __shared__ int lds[PB];
    const int bu = blockIdx.x;
    const int t = threadIdx.x;
    int v = table[bu * PB + t];
    lds[t] = v;
    __syncthreads();
    for (int off = 1; off < PB; off <<= 1) {
        int u = (t >= off) ? lds[t - off] : 0;
        __syncthreads();
        lds[t] += u;
        __syncthreads();
    }
    table[bu * PB + t] = lds[t] - v;
    if (t == PB - 1) rowsum[bu] = lds[t];
}

// ================= P2b: exclusive scan of bucket totals =================
__global__ void k_scanB(int* __restrict__ rowsum, int nb) {
    __shared__ int lds[PB];
    const int t = threadIdx.x;
    int v = (t < nb) ? rowsum[t] : 0;
    lds[t] = v;
    __syncthreads();
    for (int off = 1; off < PB; off <<= 1) {
        int u = (t >= off) ? lds[t - off] : 0;
        __syncthreads();
        lds[t] += u;
        __syncthreads();
    }
    if (t < nb) rowsum[t] = lds[t] - v;
}

// ================= P2c: add bucket base =================
__global__ void k_scanC(int* __restrict__ table, const int* __restrict__ rowsum, int L) {
    int i = blockIdx.x * 256 + threadIdx.x;
    if (i < L) table[i] += rowsum[i >> 9];  // i / PB, PB=512
}

// ================= P3: partition scatter =================
__global__ void k_pscatter(const int* __restrict__ src, const int* __restrict__ dst,
                           const int* __restrict__ excl, int* __restrict__ part,
                           int E, int nb, int chunk) {
    __shared__ int cur[MAXNB];
    for (int t = threadIdx.x; t < nb; t += 256) cur[t] = excl[t * PB + blockIdx.x];
    __syncthreads();
    int beg = blockIdx.x * chunk;
    int end = beg + chunk; if (end > E) end = E;
    for (int e = beg + threadIdx.x; e < end; e += 256) {
        int d = dst[e];
        int bu = d >> BSH;
        int pos = atomicAdd(&cur[bu], 1);
        part[pos] = ((d & (BN - 1)) << SRCBITS) | src[e];
    }
}

// ================= P4: per-bucket ELL fill + degree + dinv + pad-to-8 =================
__global__ void k_bell(const int* __restrict__ part, const int* __restrict__ excl,
                       int* __restrict__ ell, int* __restrict__ deg,
                       float* __restrict__ dinv, int E, int nb, int n) {
    __shared__ int cnt[BN];
    int b = blockIdx.x;
    for (int t = threadIdx.x; t < BN; t += 256) cnt[t] = 0;
    __syncthreads();
    int beg = excl[b * PB];
    int end = (b == nb - 1) ? E : excl[(b + 1) * PB];
    for (int i = beg + threadIdx.x; i < end; i += 256) {
        int c = part[i];
        int dl = c >> SRCBITS;
        int p = atomicAdd(&cnt[dl], 1);
        if (p < ELLW) ell[(size_t)((b << BSH) + dl) * ELLW + p] = c & SRCMASK;
    }
    __syncthreads();
    for (int t = threadIdx.x; t < BN; t += 256) {
        int node = (b << BSH) + t;
        if (node < n) {
            int dgv = cnt[t];
            int len = dgv < ELLW ? dgv : ELLW;
            int len8 = (len + 7) & ~7;      // ELLW%8==0 so len8<=ELLW
            int* r = ell + (size_t)node * ELLW;
            for (int p = len; p < len8; ++p) r[p] = n;   // pad -> zero row
            deg[node] = dgv;
            dinv[node] = rsqrtf((float)(dgv + 1));
        }
    }
}

// ================= GEMM + dinv scale -> bf16 (b128 W reads, 4-row x 4-ch register tile) ========
template<int K>
__launch_bounds__(256)
__global__ void k_gemm_bf(const float* __restrict__ x, const float* __restrict__ W,
                          const float* __restrict__ dinv, bfraw* __restrict__ g, int n) {
    __shared__ float sW[K * HID];
    for (int t = threadIdx.x; t < K * HID / 4; t += 256)
        ((float4*)sW)[t] = ((const float4*)W)[t];
    __syncthreads();
    const int wv = threadIdx.x >> 6;
    const int lane = threadIdx.x & 63;
    const int cq = lane & 15;
    const int rq = lane >> 4;
    const int base = blockIdx.x * 64 + wv * 16 + rq * 4;
    if (base >= n) return;
    if (base + 3 < n) {
        const float* xr = x + (size_t)base * K;
        float4 a0 = {0,0,0,0}, a1 = {0,0,0,0}, a2 = {0,0,0,0}, a3 = {0,0,0,0};
#pragma unroll 2
        for (int k = 0; k < K; k += 4) {
            float4 x0 = *(const float4*)(xr + k);
            float4 x1 = *(const float4*)(xr + K + k);
            float4 x2 = *(const float4*)(xr + 2 * K + k);
            float4 x3 = *(const float4*)(xr + 3 * K + k);
            const float* wp = sW + k * HID + cq * 4;
            float4 w0 = *(const float4*)(wp);
            float4 w1 = *(const float4*)(wp + HID);
            float4 w2 = *(const float4*)(wp + 2 * HID);
            float4 w3 = *(const float4*)(wp + 3 * HID);
            fma4x4(a0, x0, w0, w1, w2, w3);
            fma4x4(a1, x1, w0, w1, w2, w3);
            fma4x4(a2, x2, w0, w1, w2, w3);
            fma4x4(a3, x3, w0, w1, w2, w3);
        }
        float d0 = dinv[base], d1 = dinv[base + 1], d2 = dinv[base + 2], d3 = dinv[base + 3];
        uint2 o;
        o.x = pack2(a0.x * d0, a0.y * d0); o.y = pack2(a0.z * d0, a0.w * d0);
        *(uint2*)(g + (size_t)(base + 0) * HID + cq * 4) = o;
        o.x = pack2(a1.x * d1, a1.y * d1); o.y = pack2(a1.z * d1, a1.w * d1);
        *(uint2*)(g + (size_t)(base + 1) * HID + cq * 4) = o;
        o.x = pack2(a2.x * d2, a2.y * d2); o.y = pack2(a2.z * d2, a2.w * d2);
        *(uint2*)(g + (size_t)(base + 2) * HID + cq * 4) = o;
        o.x = pack2(a3.x * d3, a3.y * d3); o.y = pack2(a3.z * d3, a3.w * d3);
        *(uint2*)(g + (size_t)(base + 3) * HID + cq * 4) = o;
    } else {
        for (int r = 0; r < 4; ++r) {
            int row = base + r;
            if (row >= n) break;
            const float* xp = x + (size_t)row * K;
            float4 acc = {0,0,0,0};
            for (int k = 0; k < K; k += 4) {
                float4 xv = *(const float4*)(xp + k);
                const float* wp = sW + k * HID + cq * 4;
                float4 w0 = *(const float4*)(wp);
                float4 w1 = *(const float4*)(wp + HID);
                float4 w2 = *(const float4*)(wp + 2 * HID);
                float4 w3 = *(const float4*)(wp + 3 * HID);
                fma4x4(acc, xv, w0, w1, w2, w3);
            }
            float di = dinv[row];
            uint2 o;
            o.x = pack2(acc.x * di, acc.y * di); o.y = pack2(acc.z * di, acc.w * di);
            *(uint2*)(g + (size_t)row * HID + cq * 4) = o;
        }
    }
}

// ================= bf16 aggregation v3: 2 nodes/wave, 4 groups/node, 4 loads in flight ========
// lane bits: [5]=node half, [4:3]=edge group (4/node), [2:0]=channel octet.
// reduce = xor 8 + xor 16 (halves independent). FUSE: fused relu + next 64x64 GEMM, 2 nodes/wave.
template<bool FUSE>
__launch_bounds__(256)
__global__ void k_aggb(const int* __restrict__ deg, const int* __restrict__ ell,
                       const bfraw* __restrict__ g, const float* __restrict__ dinv,
                       const float* __restrict__ bias, const float* __restrict__ Wn,
                       bfraw* __restrict__ outp, int n) {
    __shared__ __align__(16) float sW[FUSE ? HID * HID : 4];
    __shared__ __align__(16) float sH[8][HID];
    if (FUSE) {
        for (int t = threadIdx.x; t < HID * HID / 4; t += 256)
            ((float4*)sW)[t] = ((const float4*)Wn)[t];
    }
    const int wv = threadIdx.x >> 6;
    const int lane = threadIdx.x & 63;
    const int half = lane >> 5;          // node within the pair
    const int grp4 = (lane >> 3) & 3;    // 4 edge groups per node
    const int cq = lane & 7;             // channel octet
    const int nodeSlot = wv * 2 + half;
    const int node = blockIdx.x * 8 + nodeSlot;
    float a0 = 0, a1 = 0, a2 = 0, a3 = 0, a4 = 0, a5 = 0, a6 = 0, a7 = 0;
    if (node < n) {
        int dg = deg[node];
        int len = dg < ELLW ? dg : ELLW;
        int len8 = (len + 7) & ~7;
        const int* row = ell + (size_t)node * ELLW;
        int j = grp4;
        for (; j + 12 < len8; j += 16) {     // 4 slots per group-iter: 4 loads in flight
            int s0 = row[j], s1 = row[j + 4], s2 = row[j + 8], s3 = row[j + 12];
            const uint4 v0 = *(const uint4*)(g + (size_t)s0 * HID + cq * 8);
            const uint4 v1 = *(const uint4*)(g + (size_t)s1 * HID + cq * 8);
            const uint4 v2 = *(const uint4*)(g + (size_t)s2 * HID + cq * 8);
            const uint4 v3 = *(const uint4*)(g + (size_t)s3 * HID + cq * 8);
            a0 += (bf_lo(v0.x) + bf_lo(v1.x)) + (bf_lo(v2.x) + bf_lo(v3.x));
            a1 += (bf_hi(v0.x) + bf_hi(v1.x)) + (bf_hi(v2.x) + bf_hi(v3.x));
            a2 += (bf_lo(v0.y) + bf_lo(v1.y)) + (bf_lo(v2.y) + bf_lo(v3.y));
            a3 += (bf_hi(v0.y) + bf_hi(v1.y)) + (bf_hi(v2.y) + bf_hi(v3.y));
            a4 += (bf_lo(v0.z) + bf_lo(v1.z)) + (bf_lo(v2.z) + bf_lo(v3.z));
            a5 += (bf_hi(v0.z) + bf_hi(v1.z)) + (bf_hi(v2.z) + bf_hi(v3.z));
            a6 += (bf_lo(v0.w) + bf_lo(v1.w)) + (bf_lo(v2.w) + bf_lo(v3.w));
            a7 += (bf_hi(v0.w) + bf_hi(v1.w)) + (bf_hi(v2.w) + bf_hi(v3.w));
        }
        for (; j < len8; j += 4) {
            int s0 = row[j];
            const uint4 v0 = *(const uint4*)(g + (size_t)s0 * HID + cq * 8);
            a0 += bf_lo(v0.x); a1 += bf_hi(v0.x);
            a2 += bf_lo(v0.y); a3 += bf_hi(v0.y);
            a4 += bf_lo(v0.z); a5 += bf_hi(v0.z);
            a6 += bf_lo(v0.w); a7 += bf_hi(v0.w);
        }
    }
    // reduce across 4 groups within each 32-lane half (bit5 never crossed)
    a0 += __shfl_xor(a0, 8);  a1 += __shfl_xor(a1, 8);  a2 += __shfl_xor(a2, 8);  a3 += __shfl_xor(a3, 8);
    a4 += __shfl_xor(a4, 8);  a5 += __shfl_xor(a5, 8);  a6 += __shfl_xor(a6, 8);  a7 += __shfl_xor(a7, 8);
    a0 += __shfl_xor(a0, 16); a1 += __shfl_xor(a1, 16); a2 += __shfl_xor(a2, 16); a3 += __shfl_xor(a3, 16);
    a4 += __shfl_xor(a4, 16); a5 += __shfl_xor(a5, 16); a6 += __shfl_xor(a6, 16); a7 += __shfl_xor(a7, 16);
    if (node < n && grp4 == 0) {
        const uint4 sv = *(const uint4*)(g + (size_t)node * HID + cq * 8);
        float di = dinv[node];
        const float4 bv0 = *(const float4*)(bias + cq * 8);
        const float4 bv1 = *(const float4*)(bias + cq * 8 + 4);
        float h0 = di * (a0 + bf_lo(sv.x)) + bv0.x;
        float h1 = di * (a1 + bf_hi(sv.x)) + bv0.y;
        float h2 = di * (a2 + bf_lo(sv.y)) + bv0.z;
        float h3 = di * (a3 + bf_hi(sv.y)) + bv0.w;
        float h4 = di * (a4 + bf_lo(sv.z)) + bv1.x;
        float h5 = di * (a5 + bf_hi(sv.z)) + bv1.y;
        float h6 = di * (a6 + bf_lo(sv.w)) + bv1.z;
        float h7 = di * (a7 + bf_hi(sv.w)) + bv1.w;
        if (!FUSE) {
            uint4 o;
            o.x = pack2(h0, h1); o.y = pack2(h2, h3);
            o.z = pack2(h4, h5); o.w = pack2(h6, h7);
            *(uint4*)(outp + (size_t)node * HID + cq * 8) = o;
        } else {
            h0 = fmaxf(h0, 0.0f); h1 = fmaxf(h1, 0.0f); h2 = fmaxf(h2, 0.0f); h3 = fmaxf(h3, 0.0f);
            h4 = fmaxf(h4, 0.0f); h5 = fmaxf(h5, 0.0f); h6 = fmaxf(h6, 0.0f); h7 = fmaxf(h7, 0.0f);
            *(float4*)(&sH[nodeSlot][cq * 8])     = make_float4(h0, h1, h2, h3);
            *(float4*)(&sH[nodeSlot][cq * 8 + 4]) = make_float4(h4, h5, h6, h7);
        }
    }
    if (FUSE) {
        __syncthreads();   // covers sW staging + sH visibility
        const int c4 = lane & 15;          // channel quad (covers all 64 ch)
        const int kh = (lane >> 4) & 1;    // k-half of 32
        float4 acc = {0, 0, 0, 0};
        if (node < n) {
            const float* hr = sH[nodeSlot];
#pragma unroll
            for (int kk = 0; kk < 32; kk += 4) {
                int k = kh * 32 + kk;
                float4 hv = *(const float4*)(hr + k);
                const float* wp = sW + k * HID + c4 * 4;
                float4 w0 = *(const float4*)(wp);
                float4 w1 = *(const float4*)(wp + HID);
                float4 w2 = *(const float4*)(wp + 2 * HID);
                float4 w3 = *(const float4*)(wp + 3 * HID);
                fma4x4(acc, hv, w0, w1, w2, w3);
            }
        }
        acc.x += __shfl_xor(acc.x, 16); acc.y += __shfl_xor(acc.y, 16);
        acc.z += __shfl_xor(acc.z, 16); acc.w += __shfl_xor(acc.w, 16);
        if (node < n && kh == 0) {
            float di = dinv[node];
            uint2 o;
            o.x = pack2(acc.x * di, acc.y * di);
            o.y = pack2(acc.z * di, acc.w * di);
            *(uint2*)(outp + (size_t)node * HID + c4 * 4) = o;
        }
    }
}

// ================= link scores from bf16 h3: 8 lanes/edge =================
__launch_bounds__(256)
__global__ void k_score_bf(const int* __restrict__ ls, const int* __restrict__ ld,
                           const bfraw* __restrict__ h, float* __restrict__ out, int EL) {
    const int wv = threadIdx.x >> 6;
    const int lane = threadIdx.x & 63;
    const int grp = lane >> 3;
    const int cq = lane & 7;
    long e = (long)blockIdx.x * 32 + wv * 8 + grp;
    if (e >= EL) return;   // group-uniform
    int s = ls[e];
    int d = ld[e];
    const uint4 va = *(const uint4*)(h + (size_t)s * HID + cq * 8);
    const uint4 vb = *(const uint4*)(h + (size_t)d * HID + cq * 8);
    float p = bf_lo(va.x) * bf_lo(vb.x) + bf_hi(va.x) * bf_hi(vb.x)
            + bf_lo(va.y) * bf_lo(vb.y) + bf_hi(va.y) * bf_hi(vb.y)
            + bf_lo(va.z) * bf_lo(vb.z) + bf_hi(va.z) * bf_hi(vb.z)
            + bf_lo(va.w) * bf_lo(vb.w) + bf_hi(va.w) * bf_hi(vb.w);
    p += __shfl_xor(p, 1);
    p += __shfl_xor(p, 2);
    p += __shfl_xor(p, 4);
    if (cq == 0) out[e] = 1.0f / (1.0f + __expf(-p));
}

// ================= fallback: proven r3 fp32 kernels =================
__global__ void k_ell_fill(const int* __restrict__ src, const int* __restrict__ dst,
                           int* __restrict__ cur, int* __restrict__ ell, int E) {
    int e = blockIdx.x * blockDim.x + threadIdx.x;
    if (e < E) {
        int d = dst[e];
        int p = atomicAdd(&cur[d], 1);
        if (p < ELLW) ell[(size_t)d * ELLW + p] = src[e];
    }
}
__global__ void k_dinv_from_deg(const int* __restrict__ deg, float* __restrict__ dinv, int n) {
    int i = blockIdx.x * blockDim.x + threadIdx.x;
    if (i < n) dinv[i] = rsqrtf((float)(deg[i] + 1));
}
template<int K>
__launch_bounds__(256)
__global__ void k_gemm_f32(const float* __restrict__ x, const float* __restrict__ W,
                           const float* __restrict__ dinv, float* __restrict__ g, int n) {
    __shared__ float sW[K * HID];
    for (int t = threadIdx.x; t < K * HID; t += 256) sW[t] = W[t];
    __syncthreads();
    const int lane = threadIdx.x & 63;
    const int rowInBlk = threadIdx.x >> 6;
    const int ROWS = 32;
    const int base = blockIdx.x * ROWS;
    for (int r = rowInBlk; r < ROWS; r += 4) {
        int i = base + r;
        if (i >= n) return;
        const float* xr = x + (size_t)i * K;
        float acc = 0.0f;
#pragma unroll
        for (int k = 0; k < K; k += 4) {
            float4 xv = *(const float4*)(xr + k);
            acc = fmaf(xv.x, sW[(k + 0) * HID + lane], acc);
            acc = fmaf(xv.y, sW[(k + 1) * HID + lane], acc);
            acc = fmaf(xv.z, sW[(k + 2) * HID + lane], acc);
            acc = fmaf(xv.w, sW[(k + 3) * HID + lane], acc);
        }
        g[(size_t)i * HID + lane] = acc * dinv[i];
    }
}
__launch_bounds__(256)
__global__ void k_agg_gemm(const int* __restrict__ deg, const int* __restrict__ ell,
                           const float* __restrict__ g, const float* __restrict__ dinv,
                           const float* __restrict__ bias, const float* __restrict__ Wn,
                           float* __restrict__ gout, int n) {
    __shared__ float sW[HID * HID];
    __shared__ float sH[4][HID];
    for (int t = threadIdx.x; t < HID * HID; t += 256) sW[t] = Wn[t];
    const int wv = threadIdx.x >> 6;
    const int lane = threadIdx.x & 63;
    const int node = blockIdx.x * 4 + wv;
    if (node < n) {
        int dg = deg[node];
        int len = dg < ELLW ? dg : ELLW;
        const int* row = ell + (size_t)node * ELLW;
        float acc = g[(size_t)node * HID + lane];
        int j = 0;
        for (; j + 4 <= len; j += 4) {
            int s0 = row[j], s1 = row[j + 1], s2 = row[j + 2], s3 = row[j + 3];
            acc += (g[(size_t)s0 * HID + lane] + g[(size_t)s1 * HID + lane]) +
                   (g[(size_t)s2 * HID + lane] + g[(size_t)s3 * HID + lane]);
        }
        for (; j < len; ++j) acc += g[(size_t)row[j] * HID + lane];
        float h = fmaxf(dinv[node] * acc + bias[lane], 0.0f);
        sH[wv][lane] = h;
    }
    __syncthreads();
    if (node < n) {
        const float* hr = sH[wv];
        float o = 0.0f;
#pragma unroll
        for (int k = 0; k < HID; k += 4) {
            o = fmaf(hr[k + 0], sW[(k + 0) * HID + lane], o);
            o = fmaf(hr[k + 1], sW[(k + 1) * HID + lane], o);
            o = fmaf(hr[k + 2], sW[(k + 2) * HID + lane], o);
            o = fmaf(hr[k + 3], sW[(k + 3) * HID + lane], o);
        }
        gout[(size_t)node * HID + lane] = o * dinv[node];
    }
}
__launch_bounds__(256)
__global__ void k_aggregate_ell(const int* __restrict__ deg, const int* __restrict__ ell,
                                const float* __restrict__ g, float* __restrict__ out,
                                const float* __restrict__ dinv, const float* __restrict__ b,
                                int n) {
    int node = (int)(((long)blockIdx.x * 256 + threadIdx.x) >> 6);
    int lane = threadIdx.x & 63;
    if (node >= n) return;
    int dg = deg[node];
    int len = dg < ELLW ? dg : ELLW;
    const int* row = ell + (size_t)node * ELLW;
    float acc = g[(size_t)node * HID + lane];
    int j = 0;
    for (; j + 4 <= len; j += 4) {
        int s0 = row[j], s1 = row[j + 1], s2 = row[j + 2], s3 = row[j + 3];
        acc += (g[(size_t)s0 * HID + lane] + g[(size_t)s1 * HID + lane]) +
               (g[(size_t)s2 * HID + lane] + g[(size_t)s3 * HID + lane]);
    }
    for (; j < len; ++j) acc += g[(size_t)row[j] * HID + lane];
    out[(size_t)node * HID + lane] = dinv[node] * acc + b[lane];
}
__launch_bounds__(256)
__global__ void k_score_f32(const int* __restrict__ ls, const int* __restrict__ ld,
                            const float* __restrict__ h, float* __restrict__ out, int EL) {
    long t = (long)blockIdx.x * 256 + threadIdx.x;
    long e = t >> 4;
    if (e >= EL) return;
    int q = (int)(t & 15);
    int s = ls[e];
    int d = ld[e];
    float4 a  = *(const float4*)(h + (size_t)s * HID + q * 4);
    float4 bb = *(const float4*)(h + (size_t)d * HID + q * 4);
    float p = a.x * bb.x + a.y * bb.y + a.z * bb.z + a.w * bb.w;
    p += __shfl_xor(p, 1);
    p += __shfl_xor(p, 2);
    p += __shfl_xor(p, 4);
    p += __shfl_xor(p, 8);
    if (q == 0) out[e] = 1.0f / (1.0f + __expf(-p));
}

static inline size_t alignup(size_t v) { return (v + 255) & ~(size_t)255; }

extern "C" void kernel_launch(void* const* d_in, const int* in_sizes, int n_in,
                              void* d_out, int out_size, void* d_ws, size_t ws_size,
                              hipStream_t stream) {
    const float* x  = (const float*)d_in[0];
    const float* W1 = (const float*)d_in[1];
    const float* b1 = (const float*)d_in[2];
    const float* W2 = (const float*)d_in[3];
    const float* b2 = (const float*)d_in[4];
    const float* W3 = (const float*)d_in[5];
    const float* b3 = (const float*)d_in[6];
    const int* ei  = (const int*)d_in[7];
    const int* eli = (const int*)d_in[8];

    const int n  = in_sizes[0] / 128;
    const int E  = in_sizes[7] / 2;
    const int EL = in_sizes[8] / 2;
    float* out = (float*)d_out;

    const int* esrc = ei;
    const int* edst = ei + E;

    const long nh = (long)n * HID;
    const int nBlk  = (n + 255) / 256;
    const int eBlk  = (E + 255) / 256;
    const int aBlk  = (n + 7) / 8;
    const int nb = (n + BN - 1) >> BSH;
    const int chunk = (E + PB - 1) / PB;

    // -------- workspace layout (bf16 main path) --------
    size_t o = 0;
    char* ws = (char*)d_ws;
    int*   table  = (int*)(ws + o); o += alignup((size_t)MAXNB * PB * 4);
    int*   rowsum = (int*)(ws + o); o += alignup((size_t)MAXNB * 4);
    int*   deg    = (int*)(ws + o); o += alignup((size_t)n * 4);
    float* dinv   = (float*)(ws + o); o += alignup((size_t)n * 4);
    int*   ell    = (int*)(ws + o); o += alignup((size_t)n * ELLW * 4);
    bfraw* bufA   = (bfraw*)(ws + o); o += alignup((nh + HID) * 2);   // +1 zero pad row
    bfraw* bufB   = (bfraw*)(ws + o); o += alignup((nh + HID) * 2);
    const size_t need_main = o;
    int* part = (int*)bufA;  // E ints <= (nh+HID)*2 bytes; dead before gemm writes bufA

    if (n <= (1 << SRCBITS) && nb <= MAXNB && (long)E * 2 <= nh + HID && ws_size >= need_main) {
        // ---- build: contention-free two-pass partition + per-bucket ELL ----
        k_hist<<<PB, 256, 0, stream>>>(edst, table, E, nb, chunk);
        k_scanA<<<nb, PB, 0, stream>>>(table, rowsum);
        k_scanB<<<1, PB, 0, stream>>>(rowsum, nb);
        k_scanC<<<(nb * PB + 255) / 256, 256, 0, stream>>>(table, rowsum, nb * PB);
        k_pscatter<<<PB, 256, 0, stream>>>(esrc, edst, table, part, E, nb, chunk);
        k_bell<<<nb, 256, 0, stream>>>(part, table, ell, deg, dinv, E, nb, n);
        k_zero_padrow<<<1, 64, 0, stream>>>(bufA, bufB, nh);

        // ---- layers (bf16 staged features, fp32 math) ----
        k_gemm_bf<128><<<(n + 63) / 64, 256, 0, stream>>>(x, W1, dinv, bufA, n);     // g1 (kills part)
        k_aggb<true ><<<aBlk, 256, 0, stream>>>(deg, ell, bufA, dinv, b1, W2, bufB, n); // g2
        k_aggb<true ><<<aBlk, 256, 0, stream>>>(deg, ell, bufB, dinv, b2, W3, bufA, n); // g3
        k_aggb<false><<<aBlk, 256, 0, stream>>>(deg, ell, bufA, dinv, b3, (const float*)0, bufB, n); // h3

        k_score_bf<<<(EL + 31) / 32, 256, 0, stream>>>(eli, eli + EL, bufB, out, EL);
    } else {
        // -------- fallback: proven r3 fp32 single-pass ELL path --------
        size_t o2 = 0;
        int*   cur   = (int*)(ws + o2);   o2 += alignup((size_t)n * 4);
        float* dinv2 = (float*)(ws + o2); o2 += alignup((size_t)n * 4);
        int*   ell2  = (int*)(ws + o2);   o2 += alignup((size_t)n * ELLW * 4);
        float* fA    = (float*)(ws + o2); o2 += alignup(nh * 4);
        float* fB    = (float*)(ws + o2); o2 += alignup(nh * 4);
        const int aBlk4 = (n + 3) / 4;

        k_zero_int<<<nBlk, 256, 0, stream>>>(cur, n);
        k_ell_fill<<<eBlk, 256, 0, stream>>>(esrc, edst, cur, ell2, E);
        k_dinv_from_deg<<<nBlk, 256, 0, stream>>>(cur, dinv2, n);

        k_gemm_f32<128><<<(n + 31) / 32, 256, 0, stream>>>(x, W1, dinv2, fA, n);
        k_agg_gemm<<<aBlk4, 256, 0, stream>>>(cur, ell2, fA, dinv2, b1, W2, fB, n);
        k_agg_gemm<<<aBlk4, 256, 0, stream>>>(cur, ell2, fB, dinv2, b2, W3, fA, n);
        k_aggregate_ell<<<aBlk4, 256, 0, stream>>>(cur, ell2, fA, fB, dinv2, b3, n);

        k_score_f32<<<(int)(((long)EL * 16 + 255) / 256), 256, 0, stream>>>(eli, eli + EL, fA, out, EL);
    }
}